// Round 10
// baseline (5607.413 us; speedup 1.0000x reference)
//
#include <hip/hip_runtime.h>
#include <hip/hip_bf16.h>

#define DMODEL 2048
#define LSEQ   2048
#define NHEAD  32
#define NKVH   8
#define DHEAD  64
#define DFF    5632
#define VOCAB  32000

typedef __attribute__((ext_vector_type(8))) short bf16x8;
typedef __attribute__((ext_vector_type(4))) float f32x4;
typedef __attribute__((ext_vector_type(8))) unsigned short ushort8;

__device__ __forceinline__ void gload_lds16(const __hip_bfloat16* g, __hip_bfloat16* l) {
  __builtin_amdgcn_global_load_lds((const void __attribute__((address_space(1)))*)g,
                                   (void __attribute__((address_space(3)))*)l, 16, 0, 0);
}

__device__ __forceinline__ float bfbits2f(unsigned short u) {
  return __uint_as_float(((unsigned int)u) << 16);
}
__device__ __forceinline__ unsigned short f2bfbits(float f) {
  unsigned int x = __float_as_uint(f);
  return (unsigned short)((x + 0x7fffu + ((x >> 16) & 1u)) >> 16);
}

// ---------------- embedding gather ----------------
__global__ __launch_bounds__(256) void embed_k(const int* __restrict__ ti,
                                               const float* __restrict__ emb,
                                               float* __restrict__ x) {
  const int row = blockIdx.x;
  const int t = threadIdx.x;
  const int tok = ti[row];
  const float4* s = (const float4*)(emb + (size_t)tok * DMODEL);
  float4* d = (float4*)(x + (size_t)row * DMODEL);
  d[t] = s[t];
  d[t + 256] = s[t + 256];
}

// ---------------- RMSNorm fp32 -> bf16 ----------------
__global__ __launch_bounds__(256) void rmsnorm_k(const float* __restrict__ x,
                                                 const float* __restrict__ w,
                                                 __hip_bfloat16* __restrict__ out) {
  const int row = blockIdx.x;
  const int t = threadIdx.x;
  const float4* xr = (const float4*)(x + (size_t)row * DMODEL);
  float4 a = xr[t];
  float4 b = xr[t + 256];
  float ss = a.x*a.x + a.y*a.y + a.z*a.z + a.w*a.w
           + b.x*b.x + b.y*b.y + b.z*b.z + b.w*b.w;
  #pragma unroll
  for (int m = 32; m >= 1; m >>= 1) ss += __shfl_xor(ss, m);
  __shared__ float red[4];
  if ((t & 63) == 0) red[t >> 6] = ss;
  __syncthreads();
  const float tot = red[0] + red[1] + red[2] + red[3];
  const float sc = rsqrtf(tot * (1.0f / DMODEL) + 1e-5f);
  const float4* w4 = (const float4*)w;
  float4 wa_ = w4[t], wb_ = w4[t + 256];
  __hip_bfloat16* o = out + (size_t)row * DMODEL;
  o[4*t + 0] = __float2bfloat16(a.x * sc * wa_.x);
  o[4*t + 1] = __float2bfloat16(a.y * sc * wa_.y);
  o[4*t + 2] = __float2bfloat16(a.z * sc * wa_.z);
  o[4*t + 3] = __float2bfloat16(a.w * sc * wa_.w);
  o[1024 + 4*t + 0] = __float2bfloat16(b.x * sc * wb_.x);
  o[1024 + 4*t + 1] = __float2bfloat16(b.y * sc * wb_.y);
  o[1024 + 4*t + 2] = __float2bfloat16(b.z * sc * wb_.z);
  o[1024 + 4*t + 3] = __float2bfloat16(b.w * sc * wb_.w);
}

// ---------------- transpose fp32 [K][N] -> bf16 [N*rstride + roff][K] ----------------
__global__ __launch_bounds__(256) void transpose_k(const float* __restrict__ src,
                                                   __hip_bfloat16* __restrict__ dst,
                                                   int K, int N, int rstride, int roff) {
  __shared__ float tile[64 * 65];
  const int kb = blockIdx.x * 64;
  const int nb = blockIdx.y * 64;
  const int t = threadIdx.x;
  #pragma unroll
  for (int i = 0; i < 16; ++i) {
    const int idx = t + 256 * i;
    const int r = idx >> 6, c = idx & 63;
    tile[r * 65 + c] = src[(size_t)(kb + r) * N + nb + c];
  }
  __syncthreads();
  #pragma unroll
  for (int i = 0; i < 16; ++i) {
    const int idx = t + 256 * i;
    const int n = idx >> 6, k = idx & 63;
    dst[((size_t)(nb + n) * rstride + roff) * K + kb + k] = __float2bfloat16(tile[k * 65 + n]);
  }
}

// ---------------- 128^2 GEMM, BK=64, conflict-free granule swizzle ----------------
// EPI: 0 = fp32 store, 1 = bf16 store, 2 = fp32 residual add
template <int EPI>
__global__ __launch_bounds__(256) void gemm_bt(const __hip_bfloat16* __restrict__ A,
                                               const __hip_bfloat16* __restrict__ Bt,
                                               float* __restrict__ Cf,
                                               __hip_bfloat16* __restrict__ Cb,
                                               int M, int N, int K) {
  __shared__ __align__(16) __hip_bfloat16 As[128 * 64];
  __shared__ __align__(16) __hip_bfloat16 Bs[128 * 64];
  const int tid = threadIdx.x;
  const int wave = tid >> 6;
  const int lane = tid & 63;
  const int nbx = M >> 7;
  const int nwg = nbx * (N >> 7);
  const int orig = blockIdx.y * nbx + blockIdx.x;
  const int wid = (orig & 7) * (nwg >> 3) + (orig >> 3);   // nwg % 8 == 0 in all uses
  const int tm = (wid % nbx) << 7;
  const int tn = (wid / nbx) << 7;
  const int wr = (wave >> 1) * 64;
  const int wc = (wave & 1) * 64;
  const int fr = lane & 15;
  const int fg = lane >> 4;
  const int r8 = lane >> 3;
  const int gsrc = ((lane & 7) ^ r8) << 3;   // pre-swizzled source granule (elems)
  const int fr7 = fr & 7;
  const f32x4 fzero = {0.f, 0.f, 0.f, 0.f};
  f32x4 acc[4][4];
  #pragma unroll
  for (int i = 0; i < 4; ++i)
    #pragma unroll
    for (int j = 0; j < 4; ++j) acc[i][j] = fzero;
  const __hip_bfloat16* gA = A + (size_t)(tm + wave * 32 + r8) * K + gsrc;
  const __hip_bfloat16* gB = Bt + (size_t)(tn + wave * 32 + r8) * K + gsrc;
  const int c0 = ((0 + fg) ^ fr7) << 3;   // ksub 0
  const int c1 = ((4 + fg) ^ fr7) << 3;   // ksub 1
  for (int k0 = 0; k0 < K; k0 += 64) {
    #pragma unroll
    for (int j = 0; j < 4; ++j) {
      gload_lds16(gA + (size_t)(j * 8) * K, &As[(wave * 32 + j * 8) * 64]);
      gload_lds16(gB + (size_t)(j * 8) * K, &Bs[(wave * 32 + j * 8) * 64]);
    }
    gA += 64; gB += 64;
    __syncthreads();
    bf16x8 af[4][2], bfr[4][2];
    #pragma unroll
    for (int i = 0; i < 4; ++i) {
      af[i][0] = *(const bf16x8*)&As[(wr + i * 16 + fr) * 64 + c0];
      af[i][1] = *(const bf16x8*)&As[(wr + i * 16 + fr) * 64 + c1];
    }
    #pragma unroll
    for (int j = 0; j < 4; ++j) {
      bfr[j][0] = *(const bf16x8*)&Bs[(wc + j * 16 + fr) * 64 + c0];
      bfr[j][1] = *(const bf16x8*)&Bs[(wc + j * 16 + fr) * 64 + c1];
    }
    #pragma unroll
    for (int ks = 0; ks < 2; ++ks)
      #pragma unroll
      for (int i = 0; i < 4; ++i)
        #pragma unroll
        for (int j = 0; j < 4; ++j)
          acc[i][j] = __builtin_amdgcn_mfma_f32_16x16x32_bf16(af[i][ks], bfr[j][ks], acc[i][j], 0, 0, 0);
    __syncthreads();
  }
  #pragma unroll
  for (int i = 0; i < 4; ++i)
    #pragma unroll
    for (int j = 0; j < 4; ++j)
      #pragma unroll
      for (int r = 0; r < 4; ++r) {
        const int row = tm + wr + i * 16 + fg * 4 + r;
        const int col = tn + wc + j * 16 + fr;
        const float v = acc[i][j][r];
        if (EPI == 0) Cf[(size_t)row * N + col] = v;
        else if (EPI == 1) Cb[(size_t)row * N + col] = __float2bfloat16(v);
        else Cf[(size_t)row * N + col] += v;
      }
}

// ---------------- 256^2 pipelined GEMM, BK=32 (2 blocks/CU) ----------------
// LDS 64 KB (2buf x 2op x 256x32 bf16) -> 2 blocks/CU, 16 waves: cross-block
// overlap fills barrier stalls. Bank plan: frag grp = fg ^ ((row>>1)&3) -> 2-way
// (free); staging source grp pre-permuted (l&3)^((l>>3)&3) (both-sides rule).
// Counted vmcnt(4) (next tile's 4 gloads stay in flight). EPI: 0 = fp32
// nontemporal store, 1 = bf16 store, 3 = fused SiLU-mul (interleaved g/u).
template <int EPI>
__global__ __launch_bounds__(512, 4) void gemm8p(const __hip_bfloat16* __restrict__ A,
                                                 const __hip_bfloat16* __restrict__ Bt,
                                                 float* __restrict__ Cf,
                                                 __hip_bfloat16* __restrict__ Cb,
                                                 int M, int N, int K) {
  __shared__ __align__(16) __hip_bfloat16 lds[2][2][256 * 32];
  const int tid = threadIdx.x;
  const int wave = tid >> 6;
  const int lane = tid & 63;
  const int nbx = M >> 8;
  const int nwg = nbx * (N >> 8);
  const int orig = blockIdx.y * nbx + blockIdx.x;
  const int wid = (orig & 7) * (nwg >> 3) + (orig >> 3);   // nwg % 8 == 0 in all uses
  const int tm = (wid % nbx) << 8;
  const int tn = (wid / nbx) << 8;
  const int wm = wave >> 2;          // 0..1
  const int wn = wave & 3;           // 0..3
  const int fr = lane & 15;
  const int fg = lane >> 4;
  const int srow = lane >> 2;                       // staging row within 16-chunk
  const int sgrp = (lane & 3) ^ ((lane >> 3) & 3);  // pre-permuted source col grp
  const size_t sK = (size_t)K;

  const __hip_bfloat16* pA = A + (size_t)(tm + wave * 32 + srow) * sK + (sgrp << 3);
  const __hip_bfloat16* pB = Bt + (size_t)(tn + wave * 32 + srow) * sK + (sgrp << 3);

  // prologue: stage tile0 -> buf0, tile1 -> buf1 (4 gloads each, per wave)
  #pragma unroll
  for (int b = 0; b < 2; ++b) {
    gload_lds16(pA, &lds[b][0][(wave * 32) * 32]);
    gload_lds16(pA + (size_t)16 * sK, &lds[b][0][(wave * 32 + 16) * 32]);
    gload_lds16(pB, &lds[b][1][(wave * 32) * 32]);
    gload_lds16(pB + (size_t)16 * sK, &lds[b][1][(wave * 32 + 16) * 32]);
    pA += 32; pB += 32;
  }

  const f32x4 fzero = {0.f, 0.f, 0.f, 0.f};
  f32x4 acc[8][4];
  #pragma unroll
  for (int i = 0; i < 8; ++i)
    #pragma unroll
    for (int j = 0; j < 4; ++j) acc[i][j] = fzero;

  const int wmo = wm * 128;
  const int wno = wn * 64;

  asm volatile("s_waitcnt vmcnt(4)" ::: "memory");   // tile0 landed
  __builtin_amdgcn_s_barrier();
  __builtin_amdgcn_sched_barrier(0);

  const int NT = K >> 5;
  for (int kt = 0; kt < NT; ++kt) {
    const int cur = kt & 1;
    const __hip_bfloat16* LA = &lds[cur][0][0];
    const __hip_bfloat16* LB = &lds[cur][1][0];
    bf16x8 av[8], bv[4];
    #pragma unroll
    for (int mi = 0; mi < 8; ++mi) {
      const int r_ = wmo + mi * 16 + fr;
      av[mi] = *(const bf16x8*)&LA[r_ * 32 + ((fg ^ ((r_ >> 1) & 3)) << 3)];
    }
    #pragma unroll
    for (int ni = 0; ni < 4; ++ni) {
      const int r_ = wno + ni * 16 + fr;
      bv[ni] = *(const bf16x8*)&LB[r_ * 32 + ((fg ^ ((r_ >> 1) & 3)) << 3)];
    }
    asm volatile("s_waitcnt lgkmcnt(0)" ::: "memory");
    __builtin_amdgcn_sched_barrier(0);
    __builtin_amdgcn_s_barrier();                    // barrier#1: buf fully consumed
    __builtin_amdgcn_sched_barrier(0);
    const bool pre = (kt + 2 < NT);
    #pragma unroll
    for (int q = 0; q < 4; ++q) {
      if (pre) {
        if (q == 0) gload_lds16(pA, &lds[cur][0][(wave * 32) * 32]);
        else if (q == 1) gload_lds16(pA + (size_t)16 * sK, &lds[cur][0][(wave * 32 + 16) * 32]);
        else if (q == 2) gload_lds16(pB, &lds[cur][1][(wave * 32) * 32]);
        else gload_lds16(pB + (size_t)16 * sK, &lds[cur][1][(wave * 32 + 16) * 32]);
      }
      const int mb = (q & 1) * 4;
      const int nb = (q >> 1) * 2;
      __builtin_amdgcn_s_setprio(1);
      #pragma unroll
      for (int mi = 0; mi < 4; ++mi)
        #pragma unroll
        for (int ni = 0; ni < 2; ++ni)
          acc[mb + mi][nb + ni] = __builtin_amdgcn_mfma_f32_16x16x32_bf16(
              av[mb + mi], bv[nb + ni], acc[mb + mi][nb + ni], 0, 0, 0);
      __builtin_amdgcn_s_setprio(0);
    }
    if (pre) { pA += 32; pB += 32; }
    if (kt + 1 < NT) {
      if (pre) asm volatile("s_waitcnt vmcnt(4)" ::: "memory");
      else     asm volatile("s_waitcnt vmcnt(0)" ::: "memory");
      __builtin_amdgcn_s_barrier();                  // barrier#2
      __builtin_amdgcn_sched_barrier(0);
    }
  }
  #pragma unroll
  for (int mf = 0; mf < 8; ++mf)
    #pragma unroll
    for (int nf = 0; nf < 4; ++nf)
      #pragma unroll
      for (int r = 0; r < 4; ++r) {
        const int row = tm + wmo + mf * 16 + fg * 4 + r;
        const int col = tn + wno + nf * 16 + fr;
        const float v = acc[mf][nf][r];
        if (EPI == 0) __builtin_nontemporal_store(v, &Cf[(size_t)row * N + col]);
        else if (EPI == 1) Cb[(size_t)row * N + col] = __float2bfloat16(v);
        else if (EPI == 3) {
          const float p = __shfl_xor(v, 1);
          if (!(fr & 1)) {
            const float sv = v / (1.f + __expf(-v)) * p;
            Cb[(size_t)row * (N >> 1) + ((tn + wno + nf * 16) >> 1) + (fr >> 1)] =
                __float2bfloat16(sv);
          }
        }
      }
}

// ---------------- RoPE in-place on q,k regions of qkv ----------------
__global__ __launch_bounds__(256) void rope_k(__hip_bfloat16* __restrict__ qkv,
                                              const float* __restrict__ cosT,
                                              const float* __restrict__ sinT) {
  const int row = blockIdx.x;   // position
  const int t = threadIdx.x;
  unsigned int* base = (unsigned int*)(qkv + (size_t)row * 3072);
  #pragma unroll
  for (int p = t; p < 1280; p += 256) {   // 40 heads (32 q + 8 k) * 32 pairs
    const int hp = p >> 5;
    const int i = p & 31;
    const unsigned int packed = base[hp * 32 + i];
    const float x0 = bfbits2f((unsigned short)(packed & 0xffffu));
    const float x1 = bfbits2f((unsigned short)(packed >> 16));
    const float c = cosT[row * 32 + i];
    const float s = sinT[row * 32 + i];
    const float r0 = x0 * c - x1 * s;
    const float r1 = x0 * s + x1 * c;
    base[hp * 32 + i] = (unsigned int)f2bfbits(r0) | ((unsigned int)f2bfbits(r1) << 16);
  }
}

// ---------------- causal flash attention, GQA 32/8, DHEAD=64 ----------------
__global__ __launch_bounds__(256) void attn_k(const __hip_bfloat16* __restrict__ qkv,
                                              __hip_bfloat16* __restrict__ out) {
  const int h = blockIdx.x;                    // 0..31
  const int qt = 31 - blockIdx.y;              // heavy blocks (large qt) first
  const int tid = threadIdx.x;
  const int wave = tid >> 6;
  const int lane = tid & 63;
  const int fr = lane & 15;
  const int fg = lane >> 4;
  const int qb = qt * 64;
  const int kcol = DMODEL + (h >> 2) * DHEAD;
  const int vcol = DMODEL + NKVH * DHEAD + (h >> 2) * DHEAD;
  __shared__ __align__(16) __hip_bfloat16 Ks[64 * 64];
  __shared__ __align__(16) __hip_bfloat16 Vt[64 * 72];
  __shared__ __align__(16) __hip_bfloat16 Ps[4][16 * 72];
  bf16x8 qf[2];
  {
    const __hip_bfloat16* qp = qkv + (size_t)(qb + wave * 16 + fr) * 3072 + h * DHEAD + fg * 8;
    qf[0] = *(const bf16x8*)qp;
    qf[1] = *(const bf16x8*)(qp + 32);
  }
  const f32x4 fzero = {0.f, 0.f, 0.f, 0.f};
  float m_run = -1e30f, l_run = 0.f;   // for q = qb + wave*16 + fr
  f32x4 o[4];
  #pragma unroll
  for (int c = 0; c < 4; ++c) o[c] = fzero;

  const int kr8 = lane >> 3;                 // K staging: row-in-8 block
  const int kgr = ((lane & 7) ^ kr8) << 3;   // pre-swizzled source granule (elems)
  const int vpr = tid >> 3;                  // V staging: row-pair 0..31
  const int vg = tid & 7;                    // col group (8 cols)
  const int myq = qb + wave * 16 + fr;
  const int fr7 = fr & 7;

  for (int t = 0; t <= qt; ++t) {
    // stage K tile via global_load_lds, linear [64][64], swizzled source granule
    {
      const __hip_bfloat16* kp = qkv + (size_t)(t * 64 + wave * 16 + kr8) * 3072 + kcol + kgr;
      gload_lds16(kp, &Ks[(wave * 16) * 64]);
      gload_lds16(kp + (size_t)8 * 3072, &Ks[(wave * 16 + 8) * 64]);
    }
    // stage V transposed [d][kv], paired kv -> b32 writes
    {
      const __hip_bfloat16* vp0 = qkv + (size_t)(t * 64 + 2 * vpr) * 3072 + vcol + vg * 8;
      ushort8 va = *(const ushort8*)vp0;
      ushort8 vb = *(const ushort8*)(vp0 + 3072);
      unsigned short* vt = (unsigned short*)Vt;
      #pragma unroll
      for (int i = 0; i < 8; ++i) {
        unsigned int pk = (unsigned int)va[i] | ((unsigned int)vb[i] << 16);
        *(unsigned int*)(vt + (vg * 8 + i) * 72 + 2 * vpr) = pk;
      }
    }
    __syncthreads();
    // S^T tile: s[c][r] = S[kv = t*64 + c*16 + fg*4 + r][q = myq]; ks-outer
    f32x4 s[4];
    #pragma unroll
    for (int c = 0; c < 4; ++c) s[c] = fzero;
    #pragma unroll
    for (int ks = 0; ks < 2; ++ks)
      #pragma unroll
      for (int c = 0; c < 4; ++c) {
        bf16x8 kf = *(const bf16x8*)&Ks[(c * 16 + fr) * 64 + (((ks * 4 + fg) ^ fr7) << 3)];
        s[c] = __builtin_amdgcn_mfma_f32_16x16x32_bf16(kf, qf[ks], s[c], 0, 0, 0);
      }
    // scale + causal mask + lane-local softmax
    float pm = -1e30f;
    #pragma unroll
    for (int c = 0; c < 4; ++c)
      #pragma unroll
      for (int r = 0; r < 4; ++r) {
        float v = s[c][r] * 0.125f;
        if (t * 64 + c * 16 + fg * 4 + r > myq) v = -1e30f;
        s[c][r] = v;
        pm = fmaxf(pm, v);
      }
    pm = fmaxf(pm, __shfl_xor(pm, 16));
    pm = fmaxf(pm, __shfl_xor(pm, 32));
    const float mn = fmaxf(m_run, pm);
    const float al = __expf(m_run - mn);
    m_run = mn;
    float rs = 0.f;
    #pragma unroll
    for (int c = 0; c < 4; ++c)
      #pragma unroll
      for (int r = 0; r < 4; ++r) {
        float p = __expf(s[c][r] - mn);
        s[c][r] = p;
        rs += p;
      }
    rs += __shfl_xor(rs, 16);
    rs += __shfl_xor(rs, 32);
    l_run = l_run * al + rs;
    float als[4];
    #pragma unroll
    for (int r = 0; r < 4; ++r) als[r] = __shfl(al, fg * 4 + r);
    #pragma unroll
    for (int c = 0; c < 4; ++c)
      #pragma unroll
      for (int r = 0; r < 4; ++r) o[c][r] *= als[r];
    // P -> per-wave LDS: lane owns q=fr, k = c*16 + fg*4 + (0..3) -> one b64 per c
    {
      unsigned short* pw = (unsigned short*)Ps[wave];
      #pragma unroll
      for (int c = 0; c < 4; ++c) {
        unsigned int lo = (unsigned int)f2bfbits(s[c][0]) | ((unsigned int)f2bfbits(s[c][1]) << 16);
        unsigned int hi = (unsigned int)f2bfbits(s[c][2]) | ((unsigned int)f2bfbits(s[c][3]) << 16);
        uint2 pk; pk.x = lo; pk.y = hi;
        *(uint2*)(pw + fr * 72 + c * 16 + fg * 4) = pk;
      }
    }
    // O += P V
    #pragma unroll
    for (int ks = 0; ks < 2; ++ks) {
      bf16x8 pf = *(const bf16x8*)&Ps[wave][fr * 72 + ks * 32 + fg * 8];
      #pragma unroll
      for (int c = 0; c < 4; ++c) {
        bf16x8 vf = *(const bf16x8*)&Vt[(c * 16 + fr) * 72 + ks * 32 + fg * 8];
        o[c] = __builtin_amdgcn_mfma_f32_16x16x32_bf16(pf, vf, o[c], 0, 0, 0);
      }
    }
    __syncthreads();
  }
  float lq[4];
  #pragma unroll
  for (int r = 0; r < 4; ++r) lq[r] = __shfl(l_run, fg * 4 + r);
  #pragma unroll
  for (int c = 0; c < 4; ++c)
    #pragma unroll
    for (int r = 0; r < 4; ++r)
      out[(size_t)(qb + wave * 16 + fg * 4 + r) * DMODEL + h * DHEAD + c * 16 + fr] =
          __float2bfloat16(o[c][r] / lq[r]);
}

extern "C" void kernel_launch(void* const* d_in, const int* in_sizes, int n_in,
                              void* d_out, int out_size, void* d_ws, size_t ws_size,
                              hipStream_t stream) {
  const int* ti = (const int*)d_in[0];
  const float* emb = (const float*)d_in[1];
  const float* wq = (const float*)d_in[2];
  const float* wk = (const float*)d_in[3];
  const float* wv = (const float*)d_in[4];
  const float* wa = (const float*)d_in[5];
  const float* w_an = (const float*)d_in[6];
  const float* w_fn = (const float*)d_in[7];
  const float* wg = (const float*)d_in[8];
  const float* wu = (const float*)d_in[9];
  const float* wd = (const float*)d_in[10];
  const float* w_on = (const float*)d_in[11];
  const float* w_out = (const float*)d_in[12];
  const float* cosT = (const float*)d_in[13];
  const float* sinT = (const float*)d_in[14];
  float* outp = (float*)d_out;

  char* ws = (char*)d_ws;
  float* x            = (float*)(ws + 0);                       // fp32 [2048][2048]
  __hip_bfloat16* h   = (__hip_bfloat16*)(ws + 16777216);       // bf16 [2048][2048]
  __hip_bfloat16* qkv = (__hip_bfloat16*)(ws + 25165824);       // bf16 [2048][3072]
  __hip_bfloat16* att = (__hip_bfloat16*)(ws + 37748736);       // bf16 [2048][2048]
  __hip_bfloat16* mb  = (__hip_bfloat16*)(ws + 92274688);       // bf16 [2048][5632]
  __hip_bfloat16* wTqkv = (__hip_bfloat16*)(ws + 115343360);    // bf16 [3072][2048]
  __hip_bfloat16* wTa   = (__hip_bfloat16*)(ws + 127926272);    // bf16 [2048][2048]
  __hip_bfloat16* wTgu  = (__hip_bfloat16*)(ws + 136314880);    // bf16 [11264][2048] interleaved g/u
  __hip_bfloat16* wTd   = (__hip_bfloat16*)(ws + 182452224);    // bf16 [2048][5632]
  __hip_bfloat16* wTout = (__hip_bfloat16*)(ws + 25165824);     // bf16 [32000][2048], overlays dead bufs
  (void)in_sizes; (void)n_in; (void)out_size; (void)ws_size;

  const dim3 blk(256);
  embed_k<<<2048, blk, 0, stream>>>(ti, emb, x);
  for (int l = 0; l < 2; ++l) {
    transpose_k<<<dim3(32, 32), blk, 0, stream>>>(wq + (size_t)l * 2048 * 2048, wTqkv, 2048, 2048, 1, 0);
    transpose_k<<<dim3(32, 8),  blk, 0, stream>>>(wk + (size_t)l * 2048 * 512, wTqkv + (size_t)2048 * 2048, 2048, 512, 1, 0);
    transpose_k<<<dim3(32, 8),  blk, 0, stream>>>(wv + (size_t)l * 2048 * 512, wTqkv + (size_t)2560 * 2048, 2048, 512, 1, 0);
    transpose_k<<<dim3(32, 32), blk, 0, stream>>>(wa + (size_t)l * 2048 * 2048, wTa, 2048, 2048, 1, 0);
    transpose_k<<<dim3(32, 88), blk, 0, stream>>>(wg + (size_t)l * 2048 * 5632, wTgu, 2048, 5632, 2, 0);
    transpose_k<<<dim3(32, 88), blk, 0, stream>>>(wu + (size_t)l * 2048 * 5632, wTgu, 2048, 5632, 2, 1);
    transpose_k<<<dim3(88, 32), blk, 0, stream>>>(wd + (size_t)l * 5632 * 2048, wTd, 5632, 2048, 1, 0);

    rmsnorm_k<<<2048, blk, 0, stream>>>(x, w_an + l * 2048, h);
    gemm_bt<1><<<dim3(16, 24), blk, 0, stream>>>(h, wTqkv, nullptr, qkv, 2048, 3072, 2048);
    rope_k<<<2048, blk, 0, stream>>>(qkv, cosT, sinT);
    attn_k<<<dim3(32, 32), blk, 0, stream>>>(qkv, att);
    gemm_bt<2><<<dim3(16, 16), blk, 0, stream>>>(att, wTa, x, nullptr, 2048, 2048, 2048);

    rmsnorm_k<<<2048, blk, 0, stream>>>(x, w_fn + l * 2048, h);
    gemm8p<3><<<dim3(8, 44), dim3(512), 0, stream>>>(h, wTgu, nullptr, mb, 2048, 11264, 2048);
    gemm_bt<2><<<dim3(16, 16), blk, 0, stream>>>(mb, wTd, x, nullptr, 2048, 2048, 5632);
  }
  transpose_k<<<dim3(32, 500), blk, 0, stream>>>(w_out, wTout, 2048, 32000, 1, 0);
  rmsnorm_k<<<2048, blk, 0, stream>>>(x, w_on, h);
  gemm8p<0><<<dim3(8, 125), dim3(512), 0, stream>>>(h, wTout, outp, nullptr, 2048, 32000, 2048);
}

// Round 11
// 1344.847 us; speedup vs baseline: 4.1696x; 4.1696x over previous
//
#include <hip/hip_runtime.h>
#include <hip/hip_bf16.h>

#define DMODEL 2048
#define LSEQ   2048
#define NHEAD  32
#define NKVH   8
#define DHEAD  64
#define DFF    5632
#define VOCAB  32000

typedef __attribute__((ext_vector_type(8))) short bf16x8;
typedef __attribute__((ext_vector_type(4))) float f32x4;
typedef __attribute__((ext_vector_type(8))) unsigned short ushort8;

__device__ __forceinline__ void gload_lds16(const __hip_bfloat16* g, __hip_bfloat16* l) {
  __builtin_amdgcn_global_load_lds((const void __attribute__((address_space(1)))*)g,
                                   (void __attribute__((address_space(3)))*)l, 16, 0, 0);
}

__device__ __forceinline__ float bfbits2f(unsigned short u) {
  return __uint_as_float(((unsigned int)u) << 16);
}
__device__ __forceinline__ unsigned short f2bfbits(float f) {
  unsigned int x = __float_as_uint(f);
  return (unsigned short)((x + 0x7fffu + ((x >> 16) & 1u)) >> 16);
}

// ---------------- embedding gather ----------------
__global__ __launch_bounds__(256) void embed_k(const int* __restrict__ ti,
                                               const float* __restrict__ emb,
                                               float* __restrict__ x) {
  const int row = blockIdx.x;
  const int t = threadIdx.x;
  const int tok = ti[row];
  const float4* s = (const float4*)(emb + (size_t)tok * DMODEL);
  float4* d = (float4*)(x + (size_t)row * DMODEL);
  d[t] = s[t];
  d[t + 256] = s[t + 256];
}

// ---------------- RMSNorm fp32 -> bf16 ----------------
__global__ __launch_bounds__(256) void rmsnorm_k(const float* __restrict__ x,
                                                 const float* __restrict__ w,
                                                 __hip_bfloat16* __restrict__ out) {
  const int row = blockIdx.x;
  const int t = threadIdx.x;
  const float4* xr = (const float4*)(x + (size_t)row * DMODEL);
  float4 a = xr[t];
  float4 b = xr[t + 256];
  float ss = a.x*a.x + a.y*a.y + a.z*a.z + a.w*a.w
           + b.x*b.x + b.y*b.y + b.z*b.z + b.w*b.w;
  #pragma unroll
  for (int m = 32; m >= 1; m >>= 1) ss += __shfl_xor(ss, m);
  __shared__ float red[4];
  if ((t & 63) == 0) red[t >> 6] = ss;
  __syncthreads();
  const float tot = red[0] + red[1] + red[2] + red[3];
  const float sc = rsqrtf(tot * (1.0f / DMODEL) + 1e-5f);
  const float4* w4 = (const float4*)w;
  float4 wa_ = w4[t], wb_ = w4[t + 256];
  __hip_bfloat16* o = out + (size_t)row * DMODEL;
  o[4*t + 0] = __float2bfloat16(a.x * sc * wa_.x);
  o[4*t + 1] = __float2bfloat16(a.y * sc * wa_.y);
  o[4*t + 2] = __float2bfloat16(a.z * sc * wa_.z);
  o[4*t + 3] = __float2bfloat16(a.w * sc * wa_.w);
  o[1024 + 4*t + 0] = __float2bfloat16(b.x * sc * wb_.x);
  o[1024 + 4*t + 1] = __float2bfloat16(b.y * sc * wb_.y);
  o[1024 + 4*t + 2] = __float2bfloat16(b.z * sc * wb_.z);
  o[1024 + 4*t + 3] = __float2bfloat16(b.w * sc * wb_.w);
}

// ---------------- transpose fp32 [K][N] -> bf16 [N*rstride + roff][K] ----------------
__global__ __launch_bounds__(256) void transpose_k(const float* __restrict__ src,
                                                   __hip_bfloat16* __restrict__ dst,
                                                   int K, int N, int rstride, int roff) {
  __shared__ float tile[64 * 65];
  const int kb = blockIdx.x * 64;
  const int nb = blockIdx.y * 64;
  const int t = threadIdx.x;
  #pragma unroll
  for (int i = 0; i < 16; ++i) {
    const int idx = t + 256 * i;
    const int r = idx >> 6, c = idx & 63;
    tile[r * 65 + c] = src[(size_t)(kb + r) * N + nb + c];
  }
  __syncthreads();
  #pragma unroll
  for (int i = 0; i < 16; ++i) {
    const int idx = t + 256 * i;
    const int n = idx >> 6, k = idx & 63;
    dst[((size_t)(nb + n) * rstride + roff) * K + kb + k] = __float2bfloat16(tile[k * 65 + n]);
  }
}

// ---------------- 128^2 GEMM, BK=64, conflict-free granule swizzle ----------------
// EPI: 0 = fp32 store, 1 = bf16 store, 2 = fp32 residual add
template <int EPI>
__global__ __launch_bounds__(256) void gemm_bt(const __hip_bfloat16* __restrict__ A,
                                               const __hip_bfloat16* __restrict__ Bt,
                                               float* __restrict__ Cf,
                                               __hip_bfloat16* __restrict__ Cb,
                                               int M, int N, int K) {
  __shared__ __align__(16) __hip_bfloat16 As[128 * 64];
  __shared__ __align__(16) __hip_bfloat16 Bs[128 * 64];
  const int tid = threadIdx.x;
  const int wave = tid >> 6;
  const int lane = tid & 63;
  const int nbx = M >> 7;
  const int nwg = nbx * (N >> 7);
  const int orig = blockIdx.y * nbx + blockIdx.x;
  const int wid = (orig & 7) * (nwg >> 3) + (orig >> 3);   // nwg % 8 == 0 in all uses
  const int tm = (wid % nbx) << 7;
  const int tn = (wid / nbx) << 7;
  const int wr = (wave >> 1) * 64;
  const int wc = (wave & 1) * 64;
  const int fr = lane & 15;
  const int fg = lane >> 4;
  const int r8 = lane >> 3;
  const int gsrc = ((lane & 7) ^ r8) << 3;   // pre-swizzled source granule (elems)
  const int fr7 = fr & 7;
  const f32x4 fzero = {0.f, 0.f, 0.f, 0.f};
  f32x4 acc[4][4];
  #pragma unroll
  for (int i = 0; i < 4; ++i)
    #pragma unroll
    for (int j = 0; j < 4; ++j) acc[i][j] = fzero;
  const __hip_bfloat16* gA = A + (size_t)(tm + wave * 32 + r8) * K + gsrc;
  const __hip_bfloat16* gB = Bt + (size_t)(tn + wave * 32 + r8) * K + gsrc;
  const int c0 = ((0 + fg) ^ fr7) << 3;   // ksub 0
  const int c1 = ((4 + fg) ^ fr7) << 3;   // ksub 1
  for (int k0 = 0; k0 < K; k0 += 64) {
    #pragma unroll
    for (int j = 0; j < 4; ++j) {
      gload_lds16(gA + (size_t)(j * 8) * K, &As[(wave * 32 + j * 8) * 64]);
      gload_lds16(gB + (size_t)(j * 8) * K, &Bs[(wave * 32 + j * 8) * 64]);
    }
    gA += 64; gB += 64;
    __syncthreads();
    bf16x8 af[4][2], bfr[4][2];
    #pragma unroll
    for (int i = 0; i < 4; ++i) {
      af[i][0] = *(const bf16x8*)&As[(wr + i * 16 + fr) * 64 + c0];
      af[i][1] = *(const bf16x8*)&As[(wr + i * 16 + fr) * 64 + c1];
    }
    #pragma unroll
    for (int j = 0; j < 4; ++j) {
      bfr[j][0] = *(const bf16x8*)&Bs[(wc + j * 16 + fr) * 64 + c0];
      bfr[j][1] = *(const bf16x8*)&Bs[(wc + j * 16 + fr) * 64 + c1];
    }
    #pragma unroll
    for (int ks = 0; ks < 2; ++ks)
      #pragma unroll
      for (int i = 0; i < 4; ++i)
        #pragma unroll
        for (int j = 0; j < 4; ++j)
          acc[i][j] = __builtin_amdgcn_mfma_f32_16x16x32_bf16(af[i][ks], bfr[j][ks], acc[i][j], 0, 0, 0);
    __syncthreads();
  }
  #pragma unroll
  for (int i = 0; i < 4; ++i)
    #pragma unroll
    for (int j = 0; j < 4; ++j)
      #pragma unroll
      for (int r = 0; r < 4; ++r) {
        const int row = tm + wr + i * 16 + fg * 4 + r;
        const int col = tn + wc + j * 16 + fr;
        const float v = acc[i][j][r];
        if (EPI == 0) Cf[(size_t)row * N + col] = v;
        else if (EPI == 1) Cb[(size_t)row * N + col] = __float2bfloat16(v);
        else Cf[(size_t)row * N + col] += v;
      }
}

// ---------------- 256x128 pipelined GEMM, BK=32, 2 blocks/CU, no spills ----------------
// 8 waves (4M x 2N), per-wave 64x64 -> acc[4][4] = 64 AGPR; operands 32 VGPR;
// total ~116 regs <= 128 (512-reg pool / 4 waves/SIMD). LDS 48 KB (A 2x16K, B 2x8K).
// Granule-XOR bank scheme (verified R10): LDS[lr][g]=global[g^((lr>>1)&3)], read
// granule fg^((row>>1)&3) -> 2-way (free). 3 gloads/wave/tile, counted vmcnt(3).
// EPI: 0 = fp32 store, 1 = bf16 store, 3 = fused SiLU-mul (interleaved g/u).
template <int EPI>
__global__ __launch_bounds__(512, 4) void gemm8p(const __hip_bfloat16* __restrict__ A,
                                                 const __hip_bfloat16* __restrict__ Bt,
                                                 float* __restrict__ Cf,
                                                 __hip_bfloat16* __restrict__ Cb,
                                                 int M, int N, int K) {
  __shared__ __align__(16) __hip_bfloat16 ldsA[2][256 * 32];
  __shared__ __align__(16) __hip_bfloat16 ldsB[2][128 * 32];
  const int tid = threadIdx.x;
  const int wave = tid >> 6;
  const int lane = tid & 63;
  const int nbx = M >> 8;
  const int nwg = nbx * (N >> 7);
  const int orig = blockIdx.y * nbx + blockIdx.x;
  const int wid = (orig & 7) * (nwg >> 3) + (orig >> 3);   // nwg % 8 == 0 in all uses
  const int tm = (wid % nbx) << 8;
  const int tn = (wid / nbx) << 7;
  const int wmo = (wave >> 1) * 64;   // 0,64,128,192
  const int wno = (wave & 1) * 64;    // 0,64
  const int fr = lane & 15;
  const int fg = lane >> 4;
  const int srow = lane >> 2;                       // staging row within 16-chunk
  const int sgrp = (lane & 3) ^ ((lane >> 3) & 3);  // pre-permuted source col grp
  const size_t sK = (size_t)K;

  const __hip_bfloat16* pA = A + (size_t)(tm + wave * 32 + srow) * sK + (sgrp << 3);
  const __hip_bfloat16* pB = Bt + (size_t)(tn + wave * 16 + srow) * sK + (sgrp << 3);

  // prologue: stage tile0 -> buf0, tile1 -> buf1 (3 gloads each, per wave)
  #pragma unroll
  for (int b = 0; b < 2; ++b) {
    gload_lds16(pA, &ldsA[b][(wave * 32) * 32]);
    gload_lds16(pA + (size_t)16 * sK, &ldsA[b][(wave * 32 + 16) * 32]);
    gload_lds16(pB, &ldsB[b][(wave * 16) * 32]);
    pA += 32; pB += 32;
  }

  const f32x4 fzero = {0.f, 0.f, 0.f, 0.f};
  f32x4 acc[4][4];
  #pragma unroll
  for (int i = 0; i < 4; ++i)
    #pragma unroll
    for (int j = 0; j < 4; ++j) acc[i][j] = fzero;

  asm volatile("s_waitcnt vmcnt(3)" ::: "memory");   // tile0 landed
  __builtin_amdgcn_s_barrier();
  __builtin_amdgcn_sched_barrier(0);

  const int NT = K >> 5;
  for (int kt = 0; kt < NT; ++kt) {
    const int cur = kt & 1;
    const __hip_bfloat16* LA = &ldsA[cur][0];
    const __hip_bfloat16* LB = &ldsB[cur][0];
    bf16x8 av[4], bv[4];
    #pragma unroll
    for (int mi = 0; mi < 4; ++mi) {
      const int r_ = wmo + mi * 16 + fr;
      av[mi] = *(const bf16x8*)&LA[r_ * 32 + ((fg ^ ((r_ >> 1) & 3)) << 3)];
    }
    #pragma unroll
    for (int ni = 0; ni < 4; ++ni) {
      const int r_ = wno + ni * 16 + fr;
      bv[ni] = *(const bf16x8*)&LB[r_ * 32 + ((fg ^ ((r_ >> 1) & 3)) << 3)];
    }
    asm volatile("s_waitcnt lgkmcnt(0)" ::: "memory");
    __builtin_amdgcn_sched_barrier(0);
    __builtin_amdgcn_s_barrier();                    // barrier#1: buf fully consumed
    __builtin_amdgcn_sched_barrier(0);
    const bool pre = (kt + 2 < NT);
    #pragma unroll
    for (int q = 0; q < 4; ++q) {
      if (pre) {
        if (q == 0) gload_lds16(pA, &ldsA[cur][(wave * 32) * 32]);
        else if (q == 1) gload_lds16(pA + (size_t)16 * sK, &ldsA[cur][(wave * 32 + 16) * 32]);
        else if (q == 2) gload_lds16(pB, &ldsB[cur][(wave * 16) * 32]);
      }
      const int mb = (q & 1) * 2;
      const int nb = (q >> 1) * 2;
      __builtin_amdgcn_s_setprio(1);
      #pragma unroll
      for (int mi = 0; mi < 2; ++mi)
        #pragma unroll
        for (int ni = 0; ni < 2; ++ni)
          acc[mb + mi][nb + ni] = __builtin_amdgcn_mfma_f32_16x16x32_bf16(
              av[mb + mi], bv[nb + ni], acc[mb + mi][nb + ni], 0, 0, 0);
      __builtin_amdgcn_s_setprio(0);
    }
    if (pre) { pA += 32; pB += 32; }
    if (kt + 1 < NT) {
      if (pre) asm volatile("s_waitcnt vmcnt(3)" ::: "memory");
      else     asm volatile("s_waitcnt vmcnt(0)" ::: "memory");
      __builtin_amdgcn_s_barrier();                  // barrier#2
      __builtin_amdgcn_sched_barrier(0);
    }
  }
  #pragma unroll
  for (int mf = 0; mf < 4; ++mf)
    #pragma unroll
    for (int nf = 0; nf < 4; ++nf)
      #pragma unroll
      for (int r = 0; r < 4; ++r) {
        const int row = tm + wmo + mf * 16 + fg * 4 + r;
        const int col = tn + wno + nf * 16 + fr;
        const float v = acc[mf][nf][r];
        if (EPI == 0) Cf[(size_t)row * N + col] = v;
        else if (EPI == 1) Cb[(size_t)row * N + col] = __float2bfloat16(v);
        else if (EPI == 3) {
          const float p = __shfl_xor(v, 1);
          if (!(fr & 1)) {
            const float sv = v / (1.f + __expf(-v)) * p;
            Cb[(size_t)row * (N >> 1) + ((tn + wno + nf * 16) >> 1) + (fr >> 1)] =
                __float2bfloat16(sv);
          }
        }
      }
}

// ---------------- RoPE in-place on q,k regions of qkv ----------------
__global__ __launch_bounds__(256) void rope_k(__hip_bfloat16* __restrict__ qkv,
                                              const float* __restrict__ cosT,
                                              const float* __restrict__ sinT) {
  const int row = blockIdx.x;   // position
  const int t = threadIdx.x;
  unsigned int* base = (unsigned int*)(qkv + (size_t)row * 3072);
  #pragma unroll
  for (int p = t; p < 1280; p += 256) {   // 40 heads (32 q + 8 k) * 32 pairs
    const int hp = p >> 5;
    const int i = p & 31;
    const unsigned int packed = base[hp * 32 + i];
    const float x0 = bfbits2f((unsigned short)(packed & 0xffffu));
    const float x1 = bfbits2f((unsigned short)(packed >> 16));
    const float c = cosT[row * 32 + i];
    const float s = sinT[row * 32 + i];
    const float r0 = x0 * c - x1 * s;
    const float r1 = x0 * s + x1 * c;
    base[hp * 32 + i] = (unsigned int)f2bfbits(r0) | ((unsigned int)f2bfbits(r1) << 16);
  }
}

// ---------------- causal flash attention, GQA 32/8, DHEAD=64 ----------------
__global__ __launch_bounds__(256) void attn_k(const __hip_bfloat16* __restrict__ qkv,
                                              __hip_bfloat16* __restrict__ out) {
  const int h = blockIdx.x;                    // 0..31
  const int qt = 31 - blockIdx.y;              // heavy blocks (large qt) first
  const int tid = threadIdx.x;
  const int wave = tid >> 6;
  const int lane = tid & 63;
  const int fr = lane & 15;
  const int fg = lane >> 4;
  const int qb = qt * 64;
  const int kcol = DMODEL + (h >> 2) * DHEAD;
  const int vcol = DMODEL + NKVH * DHEAD + (h >> 2) * DHEAD;
  __shared__ __align__(16) __hip_bfloat16 Ks[64 * 64];
  __shared__ __align__(16) __hip_bfloat16 Vt[64 * 72];
  __shared__ __align__(16) __hip_bfloat16 Ps[4][16 * 72];
  bf16x8 qf[2];
  {
    const __hip_bfloat16* qp = qkv + (size_t)(qb + wave * 16 + fr) * 3072 + h * DHEAD + fg * 8;
    qf[0] = *(const bf16x8*)qp;
    qf[1] = *(const bf16x8*)(qp + 32);
  }
  const f32x4 fzero = {0.f, 0.f, 0.f, 0.f};
  float m_run = -1e30f, l_run = 0.f;   // for q = qb + wave*16 + fr
  f32x4 o[4];
  #pragma unroll
  for (int c = 0; c < 4; ++c) o[c] = fzero;

  const int kr8 = lane >> 3;                 // K staging: row-in-8 block
  const int kgr = ((lane & 7) ^ kr8) << 3;   // pre-swizzled source granule (elems)
  const int vpr = tid >> 3;                  // V staging: row-pair 0..31
  const int vg = tid & 7;                    // col group (8 cols)
  const int myq = qb + wave * 16 + fr;
  const int fr7 = fr & 7;

  for (int t = 0; t <= qt; ++t) {
    // stage K tile via global_load_lds, linear [64][64], swizzled source granule
    {
      const __hip_bfloat16* kp = qkv + (size_t)(t * 64 + wave * 16 + kr8) * 3072 + kcol + kgr;
      gload_lds16(kp, &Ks[(wave * 16) * 64]);
      gload_lds16(kp + (size_t)8 * 3072, &Ks[(wave * 16 + 8) * 64]);
    }
    // stage V transposed [d][kv], paired kv -> b32 writes
    {
      const __hip_bfloat16* vp0 = qkv + (size_t)(t * 64 + 2 * vpr) * 3072 + vcol + vg * 8;
      ushort8 va = *(const ushort8*)vp0;
      ushort8 vb = *(const ushort8*)(vp0 + 3072);
      unsigned short* vt = (unsigned short*)Vt;
      #pragma unroll
      for (int i = 0; i < 8; ++i) {
        unsigned int pk = (unsigned int)va[i] | ((unsigned int)vb[i] << 16);
        *(unsigned int*)(vt + (vg * 8 + i) * 72 + 2 * vpr) = pk;
      }
    }
    __syncthreads();
    // S^T tile: s[c][r] = S[kv = t*64 + c*16 + fg*4 + r][q = myq]; ks-outer
    f32x4 s[4];
    #pragma unroll
    for (int c = 0; c < 4; ++c) s[c] = fzero;
    #pragma unroll
    for (int ks = 0; ks < 2; ++ks)
      #pragma unroll
      for (int c = 0; c < 4; ++c) {
        bf16x8 kf = *(const bf16x8*)&Ks[(c * 16 + fr) * 64 + (((ks * 4 + fg) ^ fr7) << 3)];
        s[c] = __builtin_amdgcn_mfma_f32_16x16x32_bf16(kf, qf[ks], s[c], 0, 0, 0);
      }
    // scale + causal mask + lane-local softmax
    float pm = -1e30f;
    #pragma unroll
    for (int c = 0; c < 4; ++c)
      #pragma unroll
      for (int r = 0; r < 4; ++r) {
        float v = s[c][r] * 0.125f;
        if (t * 64 + c * 16 + fg * 4 + r > myq) v = -1e30f;
        s[c][r] = v;
        pm = fmaxf(pm, v);
      }
    pm = fmaxf(pm, __shfl_xor(pm, 16));
    pm = fmaxf(pm, __shfl_xor(pm, 32));
    const float mn = fmaxf(m_run, pm);
    const float al = __expf(m_run - mn);
    m_run = mn;
    float rs = 0.f;
    #pragma unroll
    for (int c = 0; c < 4; ++c)
      #pragma unroll
      for (int r = 0; r < 4; ++r) {
        float p = __expf(s[c][r] - mn);
        s[c][r] = p;
        rs += p;
      }
    rs += __shfl_xor(rs, 16);
    rs += __shfl_xor(rs, 32);
    l_run = l_run * al + rs;
    float als[4];
    #pragma unroll
    for (int r = 0; r < 4; ++r) als[r] = __shfl(al, fg * 4 + r);
    #pragma unroll
    for (int c = 0; c < 4; ++c)
      #pragma unroll
      for (int r = 0; r < 4; ++r) o[c][r] *= als[r];
    // P -> per-wave LDS: lane owns q=fr, k = c*16 + fg*4 + (0..3) -> one b64 per c
    {
      unsigned short* pw = (unsigned short*)Ps[wave];
      #pragma unroll
      for (int c = 0; c < 4; ++c) {
        unsigned int lo = (unsigned int)f2bfbits(s[c][0]) | ((unsigned int)f2bfbits(s[c][1]) << 16);
        unsigned int hi = (unsigned int)f2bfbits(s[c][2]) | ((unsigned int)f2bfbits(s[c][3]) << 16);
        uint2 pk; pk.x = lo; pk.y = hi;
        *(uint2*)(pw + fr * 72 + c * 16 + fg * 4) = pk;
      }
    }
    // O += P V
    #pragma unroll
    for (int ks = 0; ks < 2; ++ks) {
      bf16x8 pf = *(const bf16x8*)&Ps[wave][fr * 72 + ks * 32 + fg * 8];
      #pragma unroll
      for (int c = 0; c < 4; ++c) {
        bf16x8 vf = *(const bf16x8*)&Vt[(c * 16 + fr) * 72 + ks * 32 + fg * 8];
        o[c] = __builtin_amdgcn_mfma_f32_16x16x32_bf16(pf, vf, o[c], 0, 0, 0);
      }
    }
    __syncthreads();
  }
  float lq[4];
  #pragma unroll
  for (int r = 0; r < 4; ++r) lq[r] = __shfl(l_run, fg * 4 + r);
  #pragma unroll
  for (int c = 0; c < 4; ++c)
    #pragma unroll
    for (int r = 0; r < 4; ++r)
      out[(size_t)(qb + wave * 16 + fg * 4 + r) * DMODEL + h * DHEAD + c * 16 + fr] =
          __float2bfloat16(o[c][r] / lq[r]);
}

extern "C" void kernel_launch(void* const* d_in, const int* in_sizes, int n_in,
                              void* d_out, int out_size, void* d_ws, size_t ws_size,
                              hipStream_t stream) {
  const int* ti = (const int*)d_in[0];
  const float* emb = (const float*)d_in[1];
  const float* wq = (const float*)d_in[2];
  const float* wk = (const float*)d_in[3];
  const float* wv = (const float*)d_in[4];
  const float* wa = (const float*)d_in[5];
  const float* w_an = (const float*)d_in[6];
  const float* w_fn = (const float*)d_in[7];
  const float* wg = (const float*)d_in[8];
  const float* wu = (const float*)d_in[9];
  const float* wd = (const float*)d_in[10];
  const float* w_on = (const float*)d_in[11];
  const float* w_out = (const float*)d_in[12];
  const float* cosT = (const float*)d_in[13];
  const float* sinT = (const float*)d_in[14];
  float* outp = (float*)d_out;

  char* ws = (char*)d_ws;
  float* x            = (float*)(ws + 0);                       // fp32 [2048][2048]
  __hip_bfloat16* h   = (__hip_bfloat16*)(ws + 16777216);       // bf16 [2048][2048]
  __hip_bfloat16* qkv = (__hip_bfloat16*)(ws + 25165824);       // bf16 [2048][3072]
  __hip_bfloat16* att = (__hip_bfloat16*)(ws + 37748736);       // bf16 [2048][2048]
  __hip_bfloat16* mb  = (__hip_bfloat16*)(ws + 92274688);       // bf16 [2048][5632]
  __hip_bfloat16* wTqkv = (__hip_bfloat16*)(ws + 115343360);    // bf16 [3072][2048]
  __hip_bfloat16* wTa   = (__hip_bfloat16*)(ws + 127926272);    // bf16 [2048][2048]
  __hip_bfloat16* wTgu  = (__hip_bfloat16*)(ws + 136314880);    // bf16 [11264][2048] interleaved g/u
  __hip_bfloat16* wTd   = (__hip_bfloat16*)(ws + 182452224);    // bf16 [2048][5632]
  __hip_bfloat16* wTout = (__hip_bfloat16*)(ws + 25165824);     // bf16 [32000][2048], overlays dead bufs
  (void)in_sizes; (void)n_in; (void)out_size; (void)ws_size;

  const dim3 blk(256);
  embed_k<<<2048, blk, 0, stream>>>(ti, emb, x);
  for (int l = 0; l < 2; ++l) {
    transpose_k<<<dim3(32, 32), blk, 0, stream>>>(wq + (size_t)l * 2048 * 2048, wTqkv, 2048, 2048, 1, 0);
    transpose_k<<<dim3(32, 8),  blk, 0, stream>>>(wk + (size_t)l * 2048 * 512, wTqkv + (size_t)2048 * 2048, 2048, 512, 1, 0);
    transpose_k<<<dim3(32, 8),  blk, 0, stream>>>(wv + (size_t)l * 2048 * 512, wTqkv + (size_t)2560 * 2048, 2048, 512, 1, 0);
    transpose_k<<<dim3(32, 32), blk, 0, stream>>>(wa + (size_t)l * 2048 * 2048, wTa, 2048, 2048, 1, 0);
    transpose_k<<<dim3(32, 88), blk, 0, stream>>>(wg + (size_t)l * 2048 * 5632, wTgu, 2048, 5632, 2, 0);
    transpose_k<<<dim3(32, 88), blk, 0, stream>>>(wu + (size_t)l * 2048 * 5632, wTgu, 2048, 5632, 2, 1);
    transpose_k<<<dim3(88, 32), blk, 0, stream>>>(wd + (size_t)l * 5632 * 2048, wTd, 5632, 2048, 1, 0);

    rmsnorm_k<<<2048, blk, 0, stream>>>(x, w_an + l * 2048, h);
    gemm_bt<1><<<dim3(16, 24), blk, 0, stream>>>(h, wTqkv, nullptr, qkv, 2048, 3072, 2048);
    rope_k<<<2048, blk, 0, stream>>>(qkv, cosT, sinT);
    attn_k<<<dim3(32, 32), blk, 0, stream>>>(qkv, att);
    gemm_bt<2><<<dim3(16, 16), blk, 0, stream>>>(att, wTa, x, nullptr, 2048, 2048, 2048);

    rmsnorm_k<<<2048, blk, 0, stream>>>(x, w_fn + l * 2048, h);
    gemm8p<3><<<dim3(8, 88), dim3(512), 0, stream>>>(h, wTgu, nullptr, mb, 2048, 11264, 2048);
    gemm_bt<2><<<dim3(16, 16), blk, 0, stream>>>(mb, wTd, x, nullptr, 2048, 2048, 5632);
  }
  transpose_k<<<dim3(32, 500), blk, 0, stream>>>(w_out, wTout, 2048, 32000, 1, 0);
  rmsnorm_k<<<2048, blk, 0, stream>>>(x, w_on, h);
  gemm8p<0><<<dim3(8, 250), dim3(512), 0, stream>>>(h, wTout, outp, nullptr, 2048, 32000, 2048);
}

// Round 12
// 1313.181 us; speedup vs baseline: 4.2701x; 1.0241x over previous
//
#include <hip/hip_runtime.h>
#include <hip/hip_bf16.h>

#define DMODEL 2048
#define LSEQ   2048
#define NHEAD  32
#define NKVH   8
#define DHEAD  64
#define DFF    5632
#define VOCAB  32000

typedef __attribute__((ext_vector_type(8))) short bf16x8;
typedef __attribute__((ext_vector_type(4))) float f32x4;
typedef __attribute__((ext_vector_type(8))) unsigned short ushort8;

__device__ __forceinline__ void gload_lds16(const __hip_bfloat16* g, __hip_bfloat16* l) {
  __builtin_amdgcn_global_load_lds((const void __attribute__((address_space(1)))*)g,
                                   (void __attribute__((address_space(3)))*)l, 16, 0, 0);
}

__device__ __forceinline__ float bfbits2f(unsigned short u) {
  return __uint_as_float(((unsigned int)u) << 16);
}
__device__ __forceinline__ unsigned short f2bfbits(float f) {
  unsigned int x = __float_as_uint(f);
  return (unsigned short)((x + 0x7fffu + ((x >> 16) & 1u)) >> 16);
}

// ---------------- embedding gather ----------------
__global__ __launch_bounds__(256) void embed_k(const int* __restrict__ ti,
                                               const float* __restrict__ emb,
                                               float* __restrict__ x) {
  const int row = blockIdx.x;
  const int t = threadIdx.x;
  const int tok = ti[row];
  const float4* s = (const float4*)(emb + (size_t)tok * DMODEL);
  float4* d = (float4*)(x + (size_t)row * DMODEL);
  d[t] = s[t];
  d[t + 256] = s[t + 256];
}

// ---------------- RMSNorm fp32 -> bf16 ----------------
__global__ __launch_bounds__(256) void rmsnorm_k(const float* __restrict__ x,
                                                 const float* __restrict__ w,
                                                 __hip_bfloat16* __restrict__ out) {
  const int row = blockIdx.x;
  const int t = threadIdx.x;
  const float4* xr = (const float4*)(x + (size_t)row * DMODEL);
  float4 a = xr[t];
  float4 b = xr[t + 256];
  float ss = a.x*a.x + a.y*a.y + a.z*a.z + a.w*a.w
           + b.x*b.x + b.y*b.y + b.z*b.z + b.w*b.w;
  #pragma unroll
  for (int m = 32; m >= 1; m >>= 1) ss += __shfl_xor(ss, m);
  __shared__ float red[4];
  if ((t & 63) == 0) red[t >> 6] = ss;
  __syncthreads();
  const float tot = red[0] + red[1] + red[2] + red[3];
  const float sc = rsqrtf(tot * (1.0f / DMODEL) + 1e-5f);
  const float4* w4 = (const float4*)w;
  float4 wa_ = w4[t], wb_ = w4[t + 256];
  __hip_bfloat16* o = out + (size_t)row * DMODEL;
  o[4*t + 0] = __float2bfloat16(a.x * sc * wa_.x);
  o[4*t + 1] = __float2bfloat16(a.y * sc * wa_.y);
  o[4*t + 2] = __float2bfloat16(a.z * sc * wa_.z);
  o[4*t + 3] = __float2bfloat16(a.w * sc * wa_.w);
  o[1024 + 4*t + 0] = __float2bfloat16(b.x * sc * wb_.x);
  o[1024 + 4*t + 1] = __float2bfloat16(b.y * sc * wb_.y);
  o[1024 + 4*t + 2] = __float2bfloat16(b.z * sc * wb_.z);
  o[1024 + 4*t + 3] = __float2bfloat16(b.w * sc * wb_.w);
}

// ---------------- transpose fp32 [K][N] -> bf16 [N*rstride + roff][K] ----------------
// Vectorized: float4 global reads (16 B/lane), ushort4 global writes (8 B/lane).
// LDS pad 65 keeps both scalar LDS phases at <=2-way bank aliasing (free).
__global__ __launch_bounds__(256) void transpose_k(const float* __restrict__ src,
                                                   __hip_bfloat16* __restrict__ dst,
                                                   int K, int N, int rstride, int roff) {
  __shared__ float tile[64 * 65];
  const int kb = blockIdx.x * 64;
  const int nb = blockIdx.y * 64;
  const int t = threadIdx.x;
  #pragma unroll
  for (int i = 0; i < 4; ++i) {
    const int idx = t + 256 * i;
    const int r = idx >> 4;             // k-row 0..63
    const int c4 = (idx & 15) << 2;     // n-col group
    const float4 v = *(const float4*)&src[(size_t)(kb + r) * N + nb + c4];
    tile[r * 65 + c4 + 0] = v.x;
    tile[r * 65 + c4 + 1] = v.y;
    tile[r * 65 + c4 + 2] = v.z;
    tile[r * 65 + c4 + 3] = v.w;
  }
  __syncthreads();
  #pragma unroll
  for (int i = 0; i < 4; ++i) {
    const int idx = t + 256 * i;
    const int n = idx >> 4;             // n-row 0..63
    const int k4 = (idx & 15) << 2;     // k group
    ushort4 o;
    o.x = f2bfbits(tile[(k4 + 0) * 65 + n]);
    o.y = f2bfbits(tile[(k4 + 1) * 65 + n]);
    o.z = f2bfbits(tile[(k4 + 2) * 65 + n]);
    o.w = f2bfbits(tile[(k4 + 3) * 65 + n]);
    *(ushort4*)&dst[((size_t)(nb + n) * rstride + roff) * K + kb + k4] = o;
  }
}

// ---------------- 128^2 GEMM, BK=64, conflict-free granule swizzle ----------------
// EPI: 0 = fp32 store, 1 = bf16 store, 2 = fp32 residual add
template <int EPI>
__global__ __launch_bounds__(256) void gemm_bt(const __hip_bfloat16* __restrict__ A,
                                               const __hip_bfloat16* __restrict__ Bt,
                                               float* __restrict__ Cf,
                                               __hip_bfloat16* __restrict__ Cb,
                                               int M, int N, int K) {
  __shared__ __align__(16) __hip_bfloat16 As[128 * 64];
  __shared__ __align__(16) __hip_bfloat16 Bs[128 * 64];
  const int tid = threadIdx.x;
  const int wave = tid >> 6;
  const int lane = tid & 63;
  const int nbx = M >> 7;
  const int nwg = nbx * (N >> 7);
  const int orig = blockIdx.y * nbx + blockIdx.x;
  const int wid = (orig & 7) * (nwg >> 3) + (orig >> 3);   // nwg % 8 == 0 in all uses
  const int tm = (wid % nbx) << 7;
  const int tn = (wid / nbx) << 7;
  const int wr = (wave >> 1) * 64;
  const int wc = (wave & 1) * 64;
  const int fr = lane & 15;
  const int fg = lane >> 4;
  const int r8 = lane >> 3;
  const int gsrc = ((lane & 7) ^ r8) << 3;   // pre-swizzled source granule (elems)
  const int fr7 = fr & 7;
  const f32x4 fzero = {0.f, 0.f, 0.f, 0.f};
  f32x4 acc[4][4];
  #pragma unroll
  for (int i = 0; i < 4; ++i)
    #pragma unroll
    for (int j = 0; j < 4; ++j) acc[i][j] = fzero;
  const __hip_bfloat16* gA = A + (size_t)(tm + wave * 32 + r8) * K + gsrc;
  const __hip_bfloat16* gB = Bt + (size_t)(tn + wave * 32 + r8) * K + gsrc;
  const int c0 = ((0 + fg) ^ fr7) << 3;   // ksub 0
  const int c1 = ((4 + fg) ^ fr7) << 3;   // ksub 1
  for (int k0 = 0; k0 < K; k0 += 64) {
    #pragma unroll
    for (int j = 0; j < 4; ++j) {
      gload_lds16(gA + (size_t)(j * 8) * K, &As[(wave * 32 + j * 8) * 64]);
      gload_lds16(gB + (size_t)(j * 8) * K, &Bs[(wave * 32 + j * 8) * 64]);
    }
    gA += 64; gB += 64;
    __syncthreads();
    bf16x8 af[4][2], bfr[4][2];
    #pragma unroll
    for (int i = 0; i < 4; ++i) {
      af[i][0] = *(const bf16x8*)&As[(wr + i * 16 + fr) * 64 + c0];
      af[i][1] = *(const bf16x8*)&As[(wr + i * 16 + fr) * 64 + c1];
    }
    #pragma unroll
    for (int j = 0; j < 4; ++j) {
      bfr[j][0] = *(const bf16x8*)&Bs[(wc + j * 16 + fr) * 64 + c0];
      bfr[j][1] = *(const bf16x8*)&Bs[(wc + j * 16 + fr) * 64 + c1];
    }
    #pragma unroll
    for (int ks = 0; ks < 2; ++ks)
      #pragma unroll
      for (int i = 0; i < 4; ++i)
        #pragma unroll
        for (int j = 0; j < 4; ++j)
          acc[i][j] = __builtin_amdgcn_mfma_f32_16x16x32_bf16(af[i][ks], bfr[j][ks], acc[i][j], 0, 0, 0);
    __syncthreads();
  }
  #pragma unroll
  for (int i = 0; i < 4; ++i)
    #pragma unroll
    for (int j = 0; j < 4; ++j)
      #pragma unroll
      for (int r = 0; r < 4; ++r) {
        const int row = tm + wr + i * 16 + fg * 4 + r;
        const int col = tn + wc + j * 16 + fr;
        const float v = acc[i][j][r];
        if (EPI == 0) Cf[(size_t)row * N + col] = v;
        else if (EPI == 1) Cb[(size_t)row * N + col] = __float2bfloat16(v);
        else Cf[(size_t)row * N + col] += v;
      }
}

// ---------------- 256^2 pipelined GEMM (R9 structure — best measured) ----------------
// EPI: 0 = fp32 store, 1 = bf16 store, 3 = fused SiLU-mul (interleaved g/u cols,
// writes bf16 [M][N/2]). Per K-tile: whole-tile ds_reads -> MFMA q0..q3 (ks-outer)
// with staging gloads interleaved per quadrant, vmcnt(8) counted drain, barrier#2.
template <int EPI>
__global__ __launch_bounds__(512, 2) void gemm8p(const __hip_bfloat16* __restrict__ A,
                                                 const __hip_bfloat16* __restrict__ Bt,
                                                 float* __restrict__ Cf,
                                                 __hip_bfloat16* __restrict__ Cb,
                                                 int M, int N, int K) {
  __shared__ __align__(16) __hip_bfloat16 lds[2][2][256 * 64];
  const int tid = threadIdx.x;
  const int wave = tid >> 6;
  const int lane = tid & 63;
  const int nbx = M >> 8;
  const int nwg = nbx * (N >> 8);
  const int orig = blockIdx.y * nbx + blockIdx.x;
  const int wid = (orig & 7) * (nwg >> 3) + (orig >> 3);   // nwg % 8 == 0 in all uses
  const int tm = (wid % nbx) << 8;
  const int tn = (wid / nbx) << 8;
  const int wm = wave >> 2;          // 0..1
  const int wn = wave & 3;           // 0..3
  const int fr = lane & 15;
  const int fg = lane >> 4;
  const int l3 = lane >> 3;
  const int l7 = lane & 7;
  const int swzcol = (l3 ^ l7) << 3; // pre-permuted source column (elements)
  const size_t sK = (size_t)K;

  const __hip_bfloat16* pA = A + (size_t)(tm + wave * 8 + l3) * sK + swzcol;
  const __hip_bfloat16* pB = Bt + (size_t)(tn + wave * 8 + l3) * sK + swzcol;

  // prologue: stage tile0 -> buf0, tile1 -> buf1 (8 loads each, per wave)
  #pragma unroll
  for (int j = 0; j < 4; ++j) {
    gload_lds16(pA + (size_t)(j * 64) * sK, &lds[0][0][(j * 64 + wave * 8) * 64]);
    gload_lds16(pB + (size_t)(j * 64) * sK, &lds[0][1][(j * 64 + wave * 8) * 64]);
  }
  pA += 64; pB += 64;
  #pragma unroll
  for (int j = 0; j < 4; ++j) {
    gload_lds16(pA + (size_t)(j * 64) * sK, &lds[1][0][(j * 64 + wave * 8) * 64]);
    gload_lds16(pB + (size_t)(j * 64) * sK, &lds[1][1][(j * 64 + wave * 8) * 64]);
  }
  pA += 64; pB += 64;

  const f32x4 fzero = {0.f, 0.f, 0.f, 0.f};
  f32x4 acc[8][4];
  #pragma unroll
  for (int i = 0; i < 8; ++i)
    #pragma unroll
    for (int j = 0; j < 4; ++j) acc[i][j] = fzero;

  const int wmo = wm * 128;
  const int wno = wn * 64;
  const int rswz = (fr & 7) << 4;
  const int ct0 = ((fg * 16) ^ rswz) >> 1;        // element offset within row, ksub 0
  const int ct1 = ((64 + fg * 16) ^ rswz) >> 1;   // ksub 1

  asm volatile("s_waitcnt vmcnt(8)" ::: "memory");   // tile0 landed
  __builtin_amdgcn_s_barrier();
  __builtin_amdgcn_sched_barrier(0);

  const int NT = K >> 6;
  for (int kt = 0; kt < NT; ++kt) {
    const int cur = kt & 1;
    const __hip_bfloat16* LA = &lds[cur][0][0];
    const __hip_bfloat16* LB = &lds[cur][1][0];
    bf16x8 av[8][2], bv[4][2];
    #pragma unroll
    for (int mi = 0; mi < 8; ++mi) {
      av[mi][0] = *(const bf16x8*)&LA[(wmo + mi * 16 + fr) * 64 + ct0];
      av[mi][1] = *(const bf16x8*)&LA[(wmo + mi * 16 + fr) * 64 + ct1];
    }
    #pragma unroll
    for (int ni = 0; ni < 4; ++ni) {
      bv[ni][0] = *(const bf16x8*)&LB[(wno + ni * 16 + fr) * 64 + ct0];
      bv[ni][1] = *(const bf16x8*)&LB[(wno + ni * 16 + fr) * 64 + ct1];
    }
    asm volatile("s_waitcnt lgkmcnt(0)" ::: "memory");
    __builtin_amdgcn_sched_barrier(0);
    __builtin_amdgcn_s_barrier();                    // barrier#1: buf fully consumed
    __builtin_amdgcn_sched_barrier(0);
    const bool pre = (kt + 2 < NT);
    #pragma unroll
    for (int q = 0; q < 4; ++q) {
      if (pre) {
        gload_lds16(pA + (size_t)(q * 64) * sK, &lds[cur][0][(q * 64 + wave * 8) * 64]);
        gload_lds16(pB + (size_t)(q * 64) * sK, &lds[cur][1][(q * 64 + wave * 8) * 64]);
      }
      const int mb = (q & 1) * 4;
      const int nb = (q >> 1) * 2;
      __builtin_amdgcn_s_setprio(1);
      #pragma unroll
      for (int ks = 0; ks < 2; ++ks)
        #pragma unroll
        for (int mi = 0; mi < 4; ++mi)
          #pragma unroll
          for (int ni = 0; ni < 2; ++ni)
            acc[mb + mi][nb + ni] = __builtin_amdgcn_mfma_f32_16x16x32_bf16(
                av[mb + mi][ks], bv[nb + ni][ks], acc[mb + mi][nb + ni], 0, 0, 0);
      __builtin_amdgcn_s_setprio(0);
    }
    if (pre) { pA += 64; pB += 64; }
    if (kt + 1 < NT) {
      if (pre) asm volatile("s_waitcnt vmcnt(8)" ::: "memory");
      else     asm volatile("s_waitcnt vmcnt(0)" ::: "memory");
      __builtin_amdgcn_s_barrier();                  // barrier#2
      __builtin_amdgcn_sched_barrier(0);
    }
  }
  #pragma unroll
  for (int mf = 0; mf < 8; ++mf)
    #pragma unroll
    for (int nf = 0; nf < 4; ++nf)
      #pragma unroll
      for (int r = 0; r < 4; ++r) {
        const int row = tm + wmo + mf * 16 + fg * 4 + r;
        const int col = tn + wno + nf * 16 + fr;
        const float v = acc[mf][nf][r];
        if (EPI == 0) Cf[(size_t)row * N + col] = v;
        else if (EPI == 1) Cb[(size_t)row * N + col] = __float2bfloat16(v);
        else if (EPI == 3) {
          const float p = __shfl_xor(v, 1);
          if (!(fr & 1)) {
            const float sv = v / (1.f + __expf(-v)) * p;
            Cb[(size_t)row * (N >> 1) + ((tn + wno + nf * 16) >> 1) + (fr >> 1)] =
                __float2bfloat16(sv);
          }
        }
      }
}

// ---------------- RoPE in-place on q,k regions of qkv ----------------
__global__ __launch_bounds__(256) void rope_k(__hip_bfloat16* __restrict__ qkv,
                                              const float* __restrict__ cosT,
                                              const float* __restrict__ sinT) {
  const int row = blockIdx.x;   // position
  const int t = threadIdx.x;
  unsigned int* base = (unsigned int*)(qkv + (size_t)row * 3072);
  #pragma unroll
  for (int p = t; p < 1280; p += 256) {   // 40 heads (32 q + 8 k) * 32 pairs
    const int hp = p >> 5;
    const int i = p & 31;
    const unsigned int packed = base[hp * 32 + i];
    const float x0 = bfbits2f((unsigned short)(packed & 0xffffu));
    const float x1 = bfbits2f((unsigned short)(packed >> 16));
    const float c = cosT[row * 32 + i];
    const float s = sinT[row * 32 + i];
    const float r0 = x0 * c - x1 * s;
    const float r1 = x0 * s + x1 * c;
    base[hp * 32 + i] = (unsigned int)f2bfbits(r0) | ((unsigned int)f2bfbits(r1) << 16);
  }
}

// ---------------- causal flash attention, GQA 32/8, DHEAD=64 ----------------
__global__ __launch_bounds__(256) void attn_k(const __hip_bfloat16* __restrict__ qkv,
                                              __hip_bfloat16* __restrict__ out) {
  const int h = blockIdx.x;                    // 0..31
  const int qt = 31 - blockIdx.y;              // heavy blocks (large qt) first
  const int tid = threadIdx.x;
  const int wave = tid >> 6;
  const int lane = tid & 63;
  const int fr = lane & 15;
  const int fg = lane >> 4;
  const int qb = qt * 64;
  const int kcol = DMODEL + (h >> 2) * DHEAD;
  const int vcol = DMODEL + NKVH * DHEAD + (h >> 2) * DHEAD;
  __shared__ __align__(16) __hip_bfloat16 Ks[64 * 64];
  __shared__ __align__(16) __hip_bfloat16 Vt[64 * 72];
  __shared__ __align__(16) __hip_bfloat16 Ps[4][16 * 72];
  bf16x8 qf[2];
  {
    const __hip_bfloat16* qp = qkv + (size_t)(qb + wave * 16 + fr) * 3072 + h * DHEAD + fg * 8;
    qf[0] = *(const bf16x8*)qp;
    qf[1] = *(const bf16x8*)(qp + 32);
  }
  const f32x4 fzero = {0.f, 0.f, 0.f, 0.f};
  float m_run = -1e30f, l_run = 0.f;   // for q = qb + wave*16 + fr
  f32x4 o[4];
  #pragma unroll
  for (int c = 0; c < 4; ++c) o[c] = fzero;

  const int kr8 = lane >> 3;                 // K staging: row-in-8 block
  const int kgr = ((lane & 7) ^ kr8) << 3;   // pre-swizzled source granule (elems)
  const int vpr = tid >> 3;                  // V staging: row-pair 0..31
  const int vg = tid & 7;                    // col group (8 cols)
  const int myq = qb + wave * 16 + fr;
  const int fr7 = fr & 7;

  for (int t = 0; t <= qt; ++t) {
    // stage K tile via global_load_lds, linear [64][64], swizzled source granule
    {
      const __hip_bfloat16* kp = qkv + (size_t)(t * 64 + wave * 16 + kr8) * 3072 + kcol + kgr;
      gload_lds16(kp, &Ks[(wave * 16) * 64]);
      gload_lds16(kp + (size_t)8 * 3072, &Ks[(wave * 16 + 8) * 64]);
    }
    // stage V transposed [d][kv], paired kv -> b32 writes
    {
      const __hip_bfloat16* vp0 = qkv + (size_t)(t * 64 + 2 * vpr) * 3072 + vcol + vg * 8;
      ushort8 va = *(const ushort8*)vp0;
      ushort8 vb = *(const ushort8*)(vp0 + 3072);
      unsigned short* vt = (unsigned short*)Vt;
      #pragma unroll
      for (int i = 0; i < 8; ++i) {
        unsigned int pk = (unsigned int)va[i] | ((unsigned int)vb[i] << 16);
        *(unsigned int*)(vt + (vg * 8 + i) * 72 + 2 * vpr) = pk;
      }
    }
    __syncthreads();
    // S^T tile: s[c][r] = S[kv = t*64 + c*16 + fg*4 + r][q = myq]; ks-outer
    f32x4 s[4];
    #pragma unroll
    for (int c = 0; c < 4; ++c) s[c] = fzero;
    #pragma unroll
    for (int ks = 0; ks < 2; ++ks)
      #pragma unroll
      for (int c = 0; c < 4; ++c) {
        bf16x8 kf = *(const bf16x8*)&Ks[(c * 16 + fr) * 64 + (((ks * 4 + fg) ^ fr7) << 3)];
        s[c] = __builtin_amdgcn_mfma_f32_16x16x32_bf16(kf, qf[ks], s[c], 0, 0, 0);
      }
    // scale + causal mask + lane-local softmax
    float pm = -1e30f;
    #pragma unroll
    for (int c = 0; c < 4; ++c)
      #pragma unroll
      for (int r = 0; r < 4; ++r) {
        float v = s[c][r] * 0.125f;
        if (t * 64 + c * 16 + fg * 4 + r > myq) v = -1e30f;
        s[c][r] = v;
        pm = fmaxf(pm, v);
      }
    pm = fmaxf(pm, __shfl_xor(pm, 16));
    pm = fmaxf(pm, __shfl_xor(pm, 32));
    const float mn = fmaxf(m_run, pm);
    const float al = __expf(m_run - mn);
    m_run = mn;
    float rs = 0.f;
    #pragma unroll
    for (int c = 0; c < 4; ++c)
      #pragma unroll
      for (int r = 0; r < 4; ++r) {
        float p = __expf(s[c][r] - mn);
        s[c][r] = p;
        rs += p;
      }
    rs += __shfl_xor(rs, 16);
    rs += __shfl_xor(rs, 32);
    l_run = l_run * al + rs;
    float als[4];
    #pragma unroll
    for (int r = 0; r < 4; ++r) als[r] = __shfl(al, fg * 4 + r);
    #pragma unroll
    for (int c = 0; c < 4; ++c)
      #pragma unroll
      for (int r = 0; r < 4; ++r) o[c][r] *= als[r];
    // P -> per-wave LDS: lane owns q=fr, k = c*16 + fg*4 + (0..3) -> one b64 per c
    {
      unsigned short* pw = (unsigned short*)Ps[wave];
      #pragma unroll
      for (int c = 0; c < 4; ++c) {
        unsigned int lo = (unsigned int)f2bfbits(s[c][0]) | ((unsigned int)f2bfbits(s[c][1]) << 16);
        unsigned int hi = (unsigned int)f2bfbits(s[c][2]) | ((unsigned int)f2bfbits(s[c][3]) << 16);
        uint2 pk; pk.x = lo; pk.y = hi;
        *(uint2*)(pw + fr * 72 + c * 16 + fg * 4) = pk;
      }
    }
    // O += P V
    #pragma unroll
    for (int ks = 0; ks < 2; ++ks) {
      bf16x8 pf = *(const bf16x8*)&Ps[wave][fr * 72 + ks * 32 + fg * 8];
      #pragma unroll
      for (int c = 0; c < 4; ++c) {
        bf16x8 vf = *(const bf16x8*)&Vt[(c * 16 + fr) * 72 + ks * 32 + fg * 8];
        o[c] = __builtin_amdgcn_mfma_f32_16x16x32_bf16(pf, vf, o[c], 0, 0, 0);
      }
    }
    __syncthreads();
  }
  float lq[4];
  #pragma unroll
  for (int r = 0; r < 4; ++r) lq[r] = __shfl(l_run, fg * 4 + r);
  #pragma unroll
  for (int c = 0; c < 4; ++c)
    #pragma unroll
    for (int r = 0; r < 4; ++r)
      out[(size_t)(qb + wave * 16 + fg * 4 + r) * DMODEL + h * DHEAD + c * 16 + fr] =
          __float2bfloat16(o[c][r] / lq[r]);
}

extern "C" void kernel_launch(void* const* d_in, const int* in_sizes, int n_in,
                              void* d_out, int out_size, void* d_ws, size_t ws_size,
                              hipStream_t stream) {
  const int* ti = (const int*)d_in[0];
  const float* emb = (const float*)d_in[1];
  const float* wq = (const float*)d_in[2];
  const float* wk = (const float*)d_in[3];
  const float* wv = (const float*)d_in[4];
  const float* wa = (const float*)d_in[5];
  const float* w_an = (const float*)d_in[6];
  const float* w_fn = (const float*)d_in[7];
  const float* wg = (const float*)d_in[8];
  const float* wu = (const float*)d_in[9];
  const float* wd = (const float*)d_in[10];
  const float* w_on = (const float*)d_in[11];
  const float* w_out = (const float*)d_in[12];
  const float* cosT = (const float*)d_in[13];
  const float* sinT = (const float*)d_in[14];
  float* outp = (float*)d_out;

  char* ws = (char*)d_ws;
  float* x            = (float*)(ws + 0);                       // fp32 [2048][2048]
  __hip_bfloat16* h   = (__hip_bfloat16*)(ws + 16777216);       // bf16 [2048][2048]
  __hip_bfloat16* qkv = (__hip_bfloat16*)(ws + 25165824);       // bf16 [2048][3072]
  __hip_bfloat16* att = (__hip_bfloat16*)(ws + 37748736);       // bf16 [2048][2048]
  __hip_bfloat16* mb  = (__hip_bfloat16*)(ws + 92274688);       // bf16 [2048][5632]
  __hip_bfloat16* wTqkv = (__hip_bfloat16*)(ws + 115343360);    // bf16 [3072][2048]
  __hip_bfloat16* wTa   = (__hip_bfloat16*)(ws + 127926272);    // bf16 [2048][2048]
  __hip_bfloat16* wTgu  = (__hip_bfloat16*)(ws + 136314880);    // bf16 [11264][2048] interleaved g/u
  __hip_bfloat16* wTd   = (__hip_bfloat16*)(ws + 182452224);    // bf16 [2048][5632]
  __hip_bfloat16* wTout = (__hip_bfloat16*)(ws + 25165824);     // bf16 [32000][2048], overlays dead bufs
  (void)in_sizes; (void)n_in; (void)out_size; (void)ws_size;

  const dim3 blk(256);
  embed_k<<<2048, blk, 0, stream>>>(ti, emb, x);
  for (int l = 0; l < 2; ++l) {
    transpose_k<<<dim3(32, 32), blk, 0, stream>>>(wq + (size_t)l * 2048 * 2048, wTqkv, 2048, 2048, 1, 0);
    transpose_k<<<dim3(32, 8),  blk, 0, stream>>>(wk + (size_t)l * 2048 * 512, wTqkv + (size_t)2048 * 2048, 2048, 512, 1, 0);
    transpose_k<<<dim3(32, 8),  blk, 0, stream>>>(wv + (size_t)l * 2048 * 512, wTqkv + (size_t)2560 * 2048, 2048, 512, 1, 0);
    transpose_k<<<dim3(32, 32), blk, 0, stream>>>(wa + (size_t)l * 2048 * 2048, wTa, 2048, 2048, 1, 0);
    transpose_k<<<dim3(32, 88), blk, 0, stream>>>(wg + (size_t)l * 2048 * 5632, wTgu, 2048, 5632, 2, 0);
    transpose_k<<<dim3(32, 88), blk, 0, stream>>>(wu + (size_t)l * 2048 * 5632, wTgu, 2048, 5632, 2, 1);
    transpose_k<<<dim3(88, 32), blk, 0, stream>>>(wd + (size_t)l * 5632 * 2048, wTd, 5632, 2048, 1, 0);

    rmsnorm_k<<<2048, blk, 0, stream>>>(x, w_an + l * 2048, h);
    gemm_bt<1><<<dim3(16, 24), blk, 0, stream>>>(h, wTqkv, nullptr, qkv, 2048, 3072, 2048);
    rope_k<<<2048, blk, 0, stream>>>(qkv, cosT, sinT);
    attn_k<<<dim3(32, 32), blk, 0, stream>>>(qkv, att);
    gemm_bt<2><<<dim3(16, 16), blk, 0, stream>>>(att, wTa, x, nullptr, 2048, 2048, 2048);

    rmsnorm_k<<<2048, blk, 0, stream>>>(x, w_fn + l * 2048, h);
    gemm8p<3><<<dim3(8, 44), dim3(512), 0, stream>>>(h, wTgu, nullptr, mb, 2048, 11264, 2048);
    gemm_bt<2><<<dim3(16, 16), blk, 0, stream>>>(mb, wTd, x, nullptr, 2048, 2048, 5632);
  }
  transpose_k<<<dim3(32, 500), blk, 0, stream>>>(w_out, wTout, 2048, 32000, 1, 0);
  rmsnorm_k<<<2048, blk, 0, stream>>>(x, w_on, h);
  gemm8p<0><<<dim3(8, 125), dim3(512), 0, stream>>>(h, wTout, outp, nullptr, 2048, 32000, 2048);
}

// Round 13
// 1280.398 us; speedup vs baseline: 4.3794x; 1.0256x over previous
//
#include <hip/hip_runtime.h>
#include <hip/hip_bf16.h>

#define DMODEL 2048
#define LSEQ   2048
#define NHEAD  32
#define NKVH   8
#define DHEAD  64
#define DFF    5632
#define VOCAB  32000

typedef __attribute__((ext_vector_type(8))) short bf16x8;
typedef __attribute__((ext_vector_type(4))) float f32x4;
typedef __attribute__((ext_vector_type(8))) unsigned short ushort8;

__device__ __forceinline__ void gload_lds16(const __hip_bfloat16* g, __hip_bfloat16* l) {
  __builtin_amdgcn_global_load_lds((const void __attribute__((address_space(1)))*)g,
                                   (void __attribute__((address_space(3)))*)l, 16, 0, 0);
}

__device__ __forceinline__ float bfbits2f(unsigned short u) {
  return __uint_as_float(((unsigned int)u) << 16);
}
__device__ __forceinline__ unsigned short f2bfbits(float f) {
  unsigned int x = __float_as_uint(f);
  return (unsigned short)((x + 0x7fffu + ((x >> 16) & 1u)) >> 16);
}

// ---------------- embedding gather ----------------
__global__ __launch_bounds__(256) void embed_k(const int* __restrict__ ti,
                                               const float* __restrict__ emb,
                                               float* __restrict__ x) {
  const int row = blockIdx.x;
  const int t = threadIdx.x;
  const int tok = ti[row];
  const float4* s = (const float4*)(emb + (size_t)tok * DMODEL);
  float4* d = (float4*)(x + (size_t)row * DMODEL);
  d[t] = s[t];
  d[t + 256] = s[t + 256];
}

// ---------------- RMSNorm fp32 -> bf16 ----------------
__global__ __launch_bounds__(256) void rmsnorm_k(const float* __restrict__ x,
                                                 const float* __restrict__ w,
                                                 __hip_bfloat16* __restrict__ out) {
  const int row = blockIdx.x;
  const int t = threadIdx.x;
  const float4* xr = (const float4*)(x + (size_t)row * DMODEL);
  float4 a = xr[t];
  float4 b = xr[t + 256];
  float ss = a.x*a.x + a.y*a.y + a.z*a.z + a.w*a.w
           + b.x*b.x + b.y*b.y + b.z*b.z + b.w*b.w;
  #pragma unroll
  for (int m = 32; m >= 1; m >>= 1) ss += __shfl_xor(ss, m);
  __shared__ float red[4];
  if ((t & 63) == 0) red[t >> 6] = ss;
  __syncthreads();
  const float tot = red[0] + red[1] + red[2] + red[3];
  const float sc = rsqrtf(tot * (1.0f / DMODEL) + 1e-5f);
  const float4* w4 = (const float4*)w;
  float4 wa_ = w4[t], wb_ = w4[t + 256];
  __hip_bfloat16* o = out + (size_t)row * DMODEL;
  o[4*t + 0] = __float2bfloat16(a.x * sc * wa_.x);
  o[4*t + 1] = __float2bfloat16(a.y * sc * wa_.y);
  o[4*t + 2] = __float2bfloat16(a.z * sc * wa_.z);
  o[4*t + 3] = __float2bfloat16(a.w * sc * wa_.w);
  o[1024 + 4*t + 0] = __float2bfloat16(b.x * sc * wb_.x);
  o[1024 + 4*t + 1] = __float2bfloat16(b.y * sc * wb_.y);
  o[1024 + 4*t + 2] = __float2bfloat16(b.z * sc * wb_.z);
  o[1024 + 4*t + 3] = __float2bfloat16(b.w * sc * wb_.w);
}

// ---------------- transpose fp32 [K][N] -> bf16 [N*rstride + roff][K] ----------------
// Vectorized: float4 global reads (16 B/lane), ushort4 global writes (8 B/lane).
__device__ __forceinline__ void transpose_tile(const float* __restrict__ src,
                                               __hip_bfloat16* __restrict__ dst,
                                               int K, int N, int rstride, int roff,
                                               int kb, int nb, int t) {
  __shared__ float tile[64 * 65];
  #pragma unroll
  for (int i = 0; i < 4; ++i) {
    const int idx = t + 256 * i;
    const int r = idx >> 4;
    const int c4 = (idx & 15) << 2;
    const float4 v = *(const float4*)&src[(size_t)(kb + r) * N + nb + c4];
    tile[r * 65 + c4 + 0] = v.x;
    tile[r * 65 + c4 + 1] = v.y;
    tile[r * 65 + c4 + 2] = v.z;
    tile[r * 65 + c4 + 3] = v.w;
  }
  __syncthreads();
  #pragma unroll
  for (int i = 0; i < 4; ++i) {
    const int idx = t + 256 * i;
    const int n = idx >> 4;
    const int k4 = (idx & 15) << 2;
    ushort4 o;
    o.x = f2bfbits(tile[(k4 + 0) * 65 + n]);
    o.y = f2bfbits(tile[(k4 + 1) * 65 + n]);
    o.z = f2bfbits(tile[(k4 + 2) * 65 + n]);
    o.w = f2bfbits(tile[(k4 + 3) * 65 + n]);
    *(ushort4*)&dst[((size_t)(nb + n) * rstride + roff) * K + kb + k4] = o;
  }
}

__global__ __launch_bounds__(256) void transpose_k(const float* __restrict__ src,
                                                   __hip_bfloat16* __restrict__ dst,
                                                   int K, int N, int rstride, int roff) {
  transpose_tile(src, dst, K, N, rstride, roff, blockIdx.x * 64, blockIdx.y * 64, threadIdx.x);
}

// Batched transpose: 7 weight matrices in one dispatch (descriptor table by value).
struct TDesc { const float* src; __hip_bfloat16* dst; int K, N, rstride, roff, ntiles, nty; };
struct TBatch { TDesc d[7]; };

__global__ __launch_bounds__(256) void transpose_batch_k(TBatch tb) {
  int bt = blockIdx.x;
  int seg = 0;
  while (seg < 6 && bt >= tb.d[seg].ntiles) { bt -= tb.d[seg].ntiles; ++seg; }
  const TDesc D = tb.d[seg];
  const int kb = (bt / D.nty) * 64;
  const int nb = (bt % D.nty) * 64;
  transpose_tile(D.src, D.dst, D.K, D.N, D.rstride, D.roff, kb, nb, threadIdx.x);
}

// ---------------- 128^2 GEMM, BK=64, conflict-free granule swizzle ----------------
// EPI: 0 = fp32 store, 1 = bf16 store, 2 = fp32 residual add,
//      4 = bf16 store with fused RoPE on cols < 2560 (qkv GEMM; interleaved pairs)
template <int EPI>
__global__ __launch_bounds__(256) void gemm_bt(const __hip_bfloat16* __restrict__ A,
                                               const __hip_bfloat16* __restrict__ Bt,
                                               float* __restrict__ Cf,
                                               __hip_bfloat16* __restrict__ Cb,
                                               int M, int N, int K,
                                               const float* __restrict__ cosT = nullptr,
                                               const float* __restrict__ sinT = nullptr) {
  __shared__ __align__(16) __hip_bfloat16 As[128 * 64];
  __shared__ __align__(16) __hip_bfloat16 Bs[128 * 64];
  const int tid = threadIdx.x;
  const int wave = tid >> 6;
  const int lane = tid & 63;
  const int nbx = M >> 7;
  const int nwg = nbx * (N >> 7);
  const int orig = blockIdx.y * nbx + blockIdx.x;
  const int wid = (orig & 7) * (nwg >> 3) + (orig >> 3);   // nwg % 8 == 0 in all uses
  const int tm = (wid % nbx) << 7;
  const int tn = (wid / nbx) << 7;
  const int wr = (wave >> 1) * 64;
  const int wc = (wave & 1) * 64;
  const int fr = lane & 15;
  const int fg = lane >> 4;
  const int r8 = lane >> 3;
  const int gsrc = ((lane & 7) ^ r8) << 3;   // pre-swizzled source granule (elems)
  const int fr7 = fr & 7;
  const f32x4 fzero = {0.f, 0.f, 0.f, 0.f};
  f32x4 acc[4][4];
  #pragma unroll
  for (int i = 0; i < 4; ++i)
    #pragma unroll
    for (int j = 0; j < 4; ++j) acc[i][j] = fzero;
  const __hip_bfloat16* gA = A + (size_t)(tm + wave * 32 + r8) * K + gsrc;
  const __hip_bfloat16* gB = Bt + (size_t)(tn + wave * 32 + r8) * K + gsrc;
  const int c0 = ((0 + fg) ^ fr7) << 3;   // ksub 0
  const int c1 = ((4 + fg) ^ fr7) << 3;   // ksub 1
  for (int k0 = 0; k0 < K; k0 += 64) {
    #pragma unroll
    for (int j = 0; j < 4; ++j) {
      gload_lds16(gA + (size_t)(j * 8) * K, &As[(wave * 32 + j * 8) * 64]);
      gload_lds16(gB + (size_t)(j * 8) * K, &Bs[(wave * 32 + j * 8) * 64]);
    }
    gA += 64; gB += 64;
    __syncthreads();
    bf16x8 af[4][2], bfr[4][2];
    #pragma unroll
    for (int i = 0; i < 4; ++i) {
      af[i][0] = *(const bf16x8*)&As[(wr + i * 16 + fr) * 64 + c0];
      af[i][1] = *(const bf16x8*)&As[(wr + i * 16 + fr) * 64 + c1];
    }
    #pragma unroll
    for (int j = 0; j < 4; ++j) {
      bfr[j][0] = *(const bf16x8*)&Bs[(wc + j * 16 + fr) * 64 + c0];
      bfr[j][1] = *(const bf16x8*)&Bs[(wc + j * 16 + fr) * 64 + c1];
    }
    #pragma unroll
    for (int ks = 0; ks < 2; ++ks)
      #pragma unroll
      for (int i = 0; i < 4; ++i)
        #pragma unroll
        for (int j = 0; j < 4; ++j)
          acc[i][j] = __builtin_amdgcn_mfma_f32_16x16x32_bf16(af[i][ks], bfr[j][ks], acc[i][j], 0, 0, 0);
    __syncthreads();
  }
  #pragma unroll
  for (int i = 0; i < 4; ++i)
    #pragma unroll
    for (int j = 0; j < 4; ++j)
      #pragma unroll
      for (int r = 0; r < 4; ++r) {
        const int row = tm + wr + i * 16 + fg * 4 + r;
        const int col = tn + wc + j * 16 + fr;
        const float v = acc[i][j][r];
        if (EPI == 0) Cf[(size_t)row * N + col] = v;
        else if (EPI == 1) Cb[(size_t)row * N + col] = __float2bfloat16(v);
        else if (EPI == 2) Cf[(size_t)row * N + col] += v;
        else if (EPI == 4) {
          // fused RoPE: cols 0..2047 = q heads, 2048..2559 = k heads, rest pass.
          const float pv = __shfl_xor(v, 1);
          float ov = v;
          if (col < 2560) {
            const int ri = (col & 63) >> 1;
            const float c = cosT[row * 32 + ri];
            const float s = sinT[row * 32 + ri];
            ov = (fr & 1) ? (pv * s + v * c) : (v * c - pv * s);
          }
          Cb[(size_t)row * N + col] = __float2bfloat16(ov);
        }
      }
}

// ---------------- 256^2 pipelined GEMM (R9 structure — best measured) ----------------
// EPI: 0 = fp32 store, 1 = bf16 store, 3 = fused SiLU-mul (interleaved g/u cols,
// writes bf16 [M][N/2]). Per K-tile: whole-tile ds_reads -> MFMA q0..q3 (ks-outer)
// with staging gloads interleaved per quadrant, vmcnt(8) counted drain, barrier#2.
template <int EPI>
__global__ __launch_bounds__(512, 2) void gemm8p(const __hip_bfloat16* __restrict__ A,
                                                 const __hip_bfloat16* __restrict__ Bt,
                                                 float* __restrict__ Cf,
                                                 __hip_bfloat16* __restrict__ Cb,
                                                 int M, int N, int K) {
  __shared__ __align__(16) __hip_bfloat16 lds[2][2][256 * 64];
  const int tid = threadIdx.x;
  const int wave = tid >> 6;
  const int lane = tid & 63;
  const int nbx = M >> 8;
  const int nwg = nbx * (N >> 8);
  const int orig = blockIdx.y * nbx + blockIdx.x;
  const int wid = (orig & 7) * (nwg >> 3) + (orig >> 3);   // nwg % 8 == 0 in all uses
  const int tm = (wid % nbx) << 8;
  const int tn = (wid / nbx) << 8;
  const int wm = wave >> 2;          // 0..1
  const int wn = wave & 3;           // 0..3
  const int fr = lane & 15;
  const int fg = lane >> 4;
  const int l3 = lane >> 3;
  const int l7 = lane & 7;
  const int swzcol = (l3 ^ l7) << 3; // pre-permuted source column (elements)
  const size_t sK = (size_t)K;

  const __hip_bfloat16* pA = A + (size_t)(tm + wave * 8 + l3) * sK + swzcol;
  const __hip_bfloat16* pB = Bt + (size_t)(tn + wave * 8 + l3) * sK + swzcol;

  // prologue: stage tile0 -> buf0, tile1 -> buf1 (8 loads each, per wave)
  #pragma unroll
  for (int j = 0; j < 4; ++j) {
    gload_lds16(pA + (size_t)(j * 64) * sK, &lds[0][0][(j * 64 + wave * 8) * 64]);
    gload_lds16(pB + (size_t)(j * 64) * sK, &lds[0][1][(j * 64 + wave * 8) * 64]);
  }
  pA += 64; pB += 64;
  #pragma unroll
  for (int j = 0; j < 4; ++j) {
    gload_lds16(pA + (size_t)(j * 64) * sK, &lds[1][0][(j * 64 + wave * 8) * 64]);
    gload_lds16(pB + (size_t)(j * 64) * sK, &lds[1][1][(j * 64 + wave * 8) * 64]);
  }
  pA += 64; pB += 64;

  const f32x4 fzero = {0.f, 0.f, 0.f, 0.f};
  f32x4 acc[8][4];
  #pragma unroll
  for (int i = 0; i < 8; ++i)
    #pragma unroll
    for (int j = 0; j < 4; ++j) acc[i][j] = fzero;

  const int wmo = wm * 128;
  const int wno = wn * 64;
  const int rswz = (fr & 7) << 4;
  const int ct0 = ((fg * 16) ^ rswz) >> 1;        // element offset within row, ksub 0
  const int ct1 = ((64 + fg * 16) ^ rswz) >> 1;   // ksub 1

  asm volatile("s_waitcnt vmcnt(8)" ::: "memory");   // tile0 landed
  __builtin_amdgcn_s_barrier();
  __builtin_amdgcn_sched_barrier(0);

  const int NT = K >> 6;
  for (int kt = 0; kt < NT; ++kt) {
    const int cur = kt & 1;
    const __hip_bfloat16* LA = &lds[cur][0][0];
    const __hip_bfloat16* LB = &lds[cur][1][0];
    bf16x8 av[8][2], bv[4][2];
    #pragma unroll
    for (int mi = 0; mi < 8; ++mi) {
      av[mi][0] = *(const bf16x8*)&LA[(wmo + mi * 16 + fr) * 64 + ct0];
      av[mi][1] = *(const bf16x8*)&LA[(wmo + mi * 16 + fr) * 64 + ct1];
    }
    #pragma unroll
    for (int ni = 0; ni < 4; ++ni) {
      bv[ni][0] = *(const bf16x8*)&LB[(wno + ni * 16 + fr) * 64 + ct0];
      bv[ni][1] = *(const bf16x8*)&LB[(wno + ni * 16 + fr) * 64 + ct1];
    }
    asm volatile("s_waitcnt lgkmcnt(0)" ::: "memory");
    __builtin_amdgcn_sched_barrier(0);
    __builtin_amdgcn_s_barrier();                    // barrier#1: buf fully consumed
    __builtin_amdgcn_sched_barrier(0);
    const bool pre = (kt + 2 < NT);
    #pragma unroll
    for (int q = 0; q < 4; ++q) {
      if (pre) {
        gload_lds16(pA + (size_t)(q * 64) * sK, &lds[cur][0][(q * 64 + wave * 8) * 64]);
        gload_lds16(pB + (size_t)(q * 64) * sK, &lds[cur][1][(q * 64 + wave * 8) * 64]);
      }
      const int mb = (q & 1) * 4;
      const int nb = (q >> 1) * 2;
      __builtin_amdgcn_s_setprio(1);
      #pragma unroll
      for (int ks = 0; ks < 2; ++ks)
        #pragma unroll
        for (int mi = 0; mi < 4; ++mi)
          #pragma unroll
          for (int ni = 0; ni < 2; ++ni)
            acc[mb + mi][nb + ni] = __builtin_amdgcn_mfma_f32_16x16x32_bf16(
                av[mb + mi][ks], bv[nb + ni][ks], acc[mb + mi][nb + ni], 0, 0, 0);
      __builtin_amdgcn_s_setprio(0);
    }
    if (pre) { pA += 64; pB += 64; }
    if (kt + 1 < NT) {
      if (pre) asm volatile("s_waitcnt vmcnt(8)" ::: "memory");
      else     asm volatile("s_waitcnt vmcnt(0)" ::: "memory");
      __builtin_amdgcn_s_barrier();                  // barrier#2
      __builtin_amdgcn_sched_barrier(0);
    }
  }
  #pragma unroll
  for (int mf = 0; mf < 8; ++mf)
    #pragma unroll
    for (int nf = 0; nf < 4; ++nf)
      #pragma unroll
      for (int r = 0; r < 4; ++r) {
        const int row = tm + wmo + mf * 16 + fg * 4 + r;
        const int col = tn + wno + nf * 16 + fr;
        const float v = acc[mf][nf][r];
        if (EPI == 0) Cf[(size_t)row * N + col] = v;
        else if (EPI == 1) Cb[(size_t)row * N + col] = __float2bfloat16(v);
        else if (EPI == 3) {
          const float p = __shfl_xor(v, 1);
          if (!(fr & 1)) {
            const float sv = v / (1.f + __expf(-v)) * p;
            Cb[(size_t)row * (N >> 1) + ((tn + wno + nf * 16) >> 1) + (fr >> 1)] =
                __float2bfloat16(sv);
          }
        }
      }
}

// ---------------- causal flash attention, GQA 32/8, DHEAD=64 ----------------
__global__ __launch_bounds__(256) void attn_k(const __hip_bfloat16* __restrict__ qkv,
                                              __hip_bfloat16* __restrict__ out) {
  const int h = blockIdx.x;                    // 0..31
  const int qt = 31 - blockIdx.y;              // heavy blocks (large qt) first
  const int tid = threadIdx.x;
  const int wave = tid >> 6;
  const int lane = tid & 63;
  const int fr = lane & 15;
  const int fg = lane >> 4;
  const int qb = qt * 64;
  const int kcol = DMODEL + (h >> 2) * DHEAD;
  const int vcol = DMODEL + NKVH * DHEAD + (h >> 2) * DHEAD;
  __shared__ __align__(16) __hip_bfloat16 Ks[64 * 64];
  __shared__ __align__(16) __hip_bfloat16 Vt[64 * 72];
  __shared__ __align__(16) __hip_bfloat16 Ps[4][16 * 72];
  bf16x8 qf[2];
  {
    const __hip_bfloat16* qp = qkv + (size_t)(qb + wave * 16 + fr) * 3072 + h * DHEAD + fg * 8;
    qf[0] = *(const bf16x8*)qp;
    qf[1] = *(const bf16x8*)(qp + 32);
  }
  const f32x4 fzero = {0.f, 0.f, 0.f, 0.f};
  float m_run = -1e30f, l_run = 0.f;   // for q = qb + wave*16 + fr
  f32x4 o[4];
  #pragma unroll
  for (int c = 0; c < 4; ++c) o[c] = fzero;

  const int kr8 = lane >> 3;                 // K staging: row-in-8 block
  const int kgr = ((lane & 7) ^ kr8) << 3;   // pre-swizzled source granule (elems)
  const int vpr = tid >> 3;                  // V staging: row-pair 0..31
  const int vg = tid & 7;                    // col group (8 cols)
  const int myq = qb + wave * 16 + fr;
  const int fr7 = fr & 7;

  for (int t = 0; t <= qt; ++t) {
    // stage K tile via global_load_lds, linear [64][64], swizzled source granule
    {
      const __hip_bfloat16* kp = qkv + (size_t)(t * 64 + wave * 16 + kr8) * 3072 + kcol + kgr;
      gload_lds16(kp, &Ks[(wave * 16) * 64]);
      gload_lds16(kp + (size_t)8 * 3072, &Ks[(wave * 16 + 8) * 64]);
    }
    // stage V transposed [d][kv], paired kv -> b32 writes
    {
      const __hip_bfloat16* vp0 = qkv + (size_t)(t * 64 + 2 * vpr) * 3072 + vcol + vg * 8;
      ushort8 va = *(const ushort8*)vp0;
      ushort8 vb = *(const ushort8*)(vp0 + 3072);
      unsigned short* vt = (unsigned short*)Vt;
      #pragma unroll
      for (int i = 0; i < 8; ++i) {
        unsigned int pk = (unsigned int)va[i] | ((unsigned int)vb[i] << 16);
        *(unsigned int*)(vt + (vg * 8 + i) * 72 + 2 * vpr) = pk;
      }
    }
    __syncthreads();
    // S^T tile: s[c][r] = S[kv = t*64 + c*16 + fg*4 + r][q = myq]; ks-outer
    f32x4 s[4];
    #pragma unroll
    for (int c = 0; c < 4; ++c) s[c] = fzero;
    #pragma unroll
    for (int ks = 0; ks < 2; ++ks)
      #pragma unroll
      for (int c = 0; c < 4; ++c) {
        bf16x8 kf = *(const bf16x8*)&Ks[(c * 16 + fr) * 64 + (((ks * 4 + fg) ^ fr7) << 3)];
        s[c] = __builtin_amdgcn_mfma_f32_16x16x32_bf16(kf, qf[ks], s[c], 0, 0, 0);
      }
    // scale + causal mask + lane-local softmax
    float pm = -1e30f;
    #pragma unroll
    for (int c = 0; c < 4; ++c)
      #pragma unroll
      for (int r = 0; r < 4; ++r) {
        float v = s[c][r] * 0.125f;
        if (t * 64 + c * 16 + fg * 4 + r > myq) v = -1e30f;
        s[c][r] = v;
        pm = fmaxf(pm, v);
      }
    pm = fmaxf(pm, __shfl_xor(pm, 16));
    pm = fmaxf(pm, __shfl_xor(pm, 32));
    const float mn = fmaxf(m_run, pm);
    const float al = __expf(m_run - mn);
    m_run = mn;
    float rs = 0.f;
    #pragma unroll
    for (int c = 0; c < 4; ++c)
      #pragma unroll
      for (int r = 0; r < 4; ++r) {
        float p = __expf(s[c][r] - mn);
        s[c][r] = p;
        rs += p;
      }
    rs += __shfl_xor(rs, 16);
    rs += __shfl_xor(rs, 32);
    l_run = l_run * al + rs;
    float als[4];
    #pragma unroll
    for (int r = 0; r < 4; ++r) als[r] = __shfl(al, fg * 4 + r);
    #pragma unroll
    for (int c = 0; c < 4; ++c)
      #pragma unroll
      for (int r = 0; r < 4; ++r) o[c][r] *= als[r];
    // P -> per-wave LDS: lane owns q=fr, k = c*16 + fg*4 + (0..3) -> one b64 per c
    {
      unsigned short* pw = (unsigned short*)Ps[wave];
      #pragma unroll
      for (int c = 0; c < 4; ++c) {
        unsigned int lo = (unsigned int)f2bfbits(s[c][0]) | ((unsigned int)f2bfbits(s[c][1]) << 16);
        unsigned int hi = (unsigned int)f2bfbits(s[c][2]) | ((unsigned int)f2bfbits(s[c][3]) << 16);
        uint2 pk; pk.x = lo; pk.y = hi;
        *(uint2*)(pw + fr * 72 + c * 16 + fg * 4) = pk;
      }
    }
    // O += P V
    #pragma unroll
    for (int ks = 0; ks < 2; ++ks) {
      bf16x8 pf = *(const bf16x8*)&Ps[wave][fr * 72 + ks * 32 + fg * 8];
      #pragma unroll
      for (int c = 0; c < 4; ++c) {
        bf16x8 vf = *(const bf16x8*)&Vt[(c * 16 + fr) * 72 + ks * 32 + fg * 8];
        o[c] = __builtin_amdgcn_mfma_f32_16x16x32_bf16(pf, vf, o[c], 0, 0, 0);
      }
    }
    __syncthreads();
  }
  float lq[4];
  #pragma unroll
  for (int r = 0; r < 4; ++r) lq[r] = __shfl(l_run, fg * 4 + r);
  #pragma unroll
  for (int c = 0; c < 4; ++c)
    #pragma unroll
    for (int r = 0; r < 4; ++r)
      out[(size_t)(qb + wave * 16 + fg * 4 + r) * DMODEL + h * DHEAD + c * 16 + fr] =
          __float2bfloat16(o[c][r] / lq[r]);
}

extern "C" void kernel_launch(void* const* d_in, const int* in_sizes, int n_in,
                              void* d_out, int out_size, void* d_ws, size_t ws_size,
                              hipStream_t stream) {
  const int* ti = (const int*)d_in[0];
  const float* emb = (const float*)d_in[1];
  const float* wq = (const float*)d_in[2];
  const float* wk = (const float*)d_in[3];
  const float* wv = (const float*)d_in[4];
  const float* wa = (const float*)d_in[5];
  const float* w_an = (const float*)d_in[6];
  const float* w_fn = (const float*)d_in[7];
  const float* wg = (const float*)d_in[8];
  const float* wu = (const float*)d_in[9];
  const float* wd = (const float*)d_in[10];
  const float* w_on = (const float*)d_in[11];
  const float* w_out = (const float*)d_in[12];
  const float* cosT = (const float*)d_in[13];
  const float* sinT = (const float*)d_in[14];
  float* outp = (float*)d_out;

  char* ws = (char*)d_ws;
  float* x            = (float*)(ws + 0);                       // fp32 [2048][2048]
  __hip_bfloat16* h   = (__hip_bfloat16*)(ws + 16777216);       // bf16 [2048][2048]
  __hip_bfloat16* qkv = (__hip_bfloat16*)(ws + 25165824);       // bf16 [2048][3072]
  __hip_bfloat16* att = (__hip_bfloat16*)(ws + 37748736);       // bf16 [2048][2048]
  __hip_bfloat16* mb  = (__hip_bfloat16*)(ws + 92274688);       // bf16 [2048][5632]
  __hip_bfloat16* wTqkv = (__hip_bfloat16*)(ws + 115343360);    // bf16 [3072][2048]
  __hip_bfloat16* wTa   = (__hip_bfloat16*)(ws + 127926272);    // bf16 [2048][2048]
  __hip_bfloat16* wTgu  = (__hip_bfloat16*)(ws + 136314880);    // bf16 [11264][2048] interleaved g/u
  __hip_bfloat16* wTd   = (__hip_bfloat16*)(ws + 182452224);    // bf16 [2048][5632]
  __hip_bfloat16* wTout = (__hip_bfloat16*)(ws + 25165824);     // bf16 [32000][2048], overlays dead bufs
  (void)in_sizes; (void)n_in; (void)out_size; (void)ws_size;

  const dim3 blk(256);
  embed_k<<<2048, blk, 0, stream>>>(ti, emb, x);
  for (int l = 0; l < 2; ++l) {
    // one batched transpose dispatch for all 7 weight matrices of this layer
    TBatch tb;
    tb.d[0] = { wq + (size_t)l * 2048 * 2048, wTqkv,                          2048, 2048, 1, 0, 32 * 32, 32 };
    tb.d[1] = { wk + (size_t)l * 2048 * 512,  wTqkv + (size_t)2048 * 2048,    2048, 512,  1, 0, 32 * 8,  8  };
    tb.d[2] = { wv + (size_t)l * 2048 * 512,  wTqkv + (size_t)2560 * 2048,    2048, 512,  1, 0, 32 * 8,  8  };
    tb.d[3] = { wa + (size_t)l * 2048 * 2048, wTa,                            2048, 2048, 1, 0, 32 * 32, 32 };
    tb.d[4] = { wg + (size_t)l * 2048 * 5632, wTgu,                           2048, 5632, 2, 0, 32 * 88, 88 };
    tb.d[5] = { wu + (size_t)l * 2048 * 5632, wTgu,                           2048, 5632, 2, 1, 32 * 88, 88 };
    tb.d[6] = { wd + (size_t)l * 5632 * 2048, wTd,                            5632, 2048, 1, 0, 88 * 32, 32 };
    const int ntt = 1024 + 256 + 256 + 1024 + 2816 + 2816 + 2816;
    transpose_batch_k<<<ntt, blk, 0, stream>>>(tb);

    rmsnorm_k<<<2048, blk, 0, stream>>>(x, w_an + l * 2048, h);
    gemm_bt<4><<<dim3(16, 24), blk, 0, stream>>>(h, wTqkv, nullptr, qkv, 2048, 3072, 2048, cosT, sinT);
    attn_k<<<dim3(32, 32), blk, 0, stream>>>(qkv, att);
    gemm_bt<2><<<dim3(16, 16), blk, 0, stream>>>(att, wTa, x, nullptr, 2048, 2048, 2048);

    rmsnorm_k<<<2048, blk, 0, stream>>>(x, w_fn + l * 2048, h);
    gemm8p<3><<<dim3(8, 44), dim3(512), 0, stream>>>(h, wTgu, nullptr, mb, 2048, 11264, 2048);
    gemm_bt<2><<<dim3(16, 16), blk, 0, stream>>>(mb, wTd, x, nullptr, 2048, 2048, 5632);
  }
  transpose_k<<<dim3(32, 500), blk, 0, stream>>>(w_out, wTout, 2048, 32000, 1, 0);
  rmsnorm_k<<<2048, blk, 0, stream>>>(x, w_on, h);
  gemm8p<0><<<dim3(8, 125), dim3(512), 0, stream>>>(h, wTout, outp, nullptr, 2048, 32000, 2048);
}